// Round 7
// baseline (208.509 us; speedup 1.0000x reference)
//
#include <hip/hip_runtime.h>
#include <hip/hip_fp16.h>

typedef __attribute__((ext_vector_type(8))) _Float16 half8;
typedef __attribute__((ext_vector_type(2))) _Float16 h2v;
typedef __attribute__((ext_vector_type(4))) float f32x4;
typedef __attribute__((ext_vector_type(4))) unsigned short u16x4;

#define NTT 1000
#define NSB 500
#define WARM 639

__device__ __forceinline__ float fsig(float x) {
  return __builtin_amdgcn_rcpf(1.f + __expf(-x));
}
// tanh(x) = 2/(1+e^(-2x)) - 1 ; branchless, inf-safe (f32)
__device__ __forceinline__ float ftanh(float x) {
  float e = __expf(-2.f * x);
  return fmaf(2.f, __builtin_amdgcn_rcpf(1.f + e), -1.f);
}
__device__ __forceinline__ float h2f(unsigned short u) {
  __half_raw hr; hr.x = u;
  return __half2float((__half)hr);
}
__device__ __forceinline__ __half2 u2h(unsigned int u) {
  __half2 h; *(unsigned int*)&h = u; return h;
}
__device__ __forceinline__ unsigned int h2u(__half2 h) {
  return *(unsigned int*)&h;
}
// packed f16 min (no __hmin2 in HIP headers) -> v_pk_min_f16
__device__ __forceinline__ __half2 hmin2(__half2 a, __half2 b) {
  h2v av = *(h2v*)&a, bv = *(h2v*)&b;
  h2v r = __builtin_elementwise_min(av, bv);
  return *(__half2*)&r;
}

// ---- prep: Wt2 -> f16 transposed XOR-swizzled [48][256]; Wt1 rows0-5 -> f16 ----
__global__ void prep_bt_kernel(const float* __restrict__ Wt2,
                               const float* __restrict__ Wt1,
                               _Float16* __restrict__ BT,
                               _Float16* __restrict__ W1h) {
  int i = blockIdx.x * 256 + threadIdx.x;
  if (i < 48 * 256) {
    int o = i >> 8, k = i & 255;
    int byte = o * 512 + ((k * 2) ^ ((o & 7) << 4));
    *(_Float16*)((char*)BT + byte) = (_Float16)Wt2[k * 48 + o];
  }
  if (i < 1536) W1h[i] = (_Float16)Wt1[i];   // rows 0..5 of Wt1 = first 1536
}

// ------------- static per-basin params (one block per basin) -------------
__global__ __launch_bounds__(256) void static_kernel(
    const float* __restrict__ xc,
    const float* __restrict__ Wr1, const float* __restrict__ br1,
    const float* __restrict__ Wr2, const float* __restrict__ br2,
    const float* __restrict__ Ww1, const float* __restrict__ bw1,
    const float* __restrict__ Ww2, const float* __restrict__ bw2,
    const float* __restrict__ Wt1, const float* __restrict__ bt1,
    _Float16* __restrict__ c_gh, float* __restrict__ params,
    float* __restrict__ rg)
{
  int s = blockIdx.x, tid = threadIdx.x;
  __shared__ float xcs[32];
  __shared__ float hw[256], hr[256];
  __shared__ float wout[112], rout[256];
  if (tid < 32) xcs[tid] = xc[s * 32 + tid];
  __syncthreads();
  {
    float aw = bw1[tid], ar = br1[tid], ac = bt1[tid];
    #pragma unroll 8
    for (int g = 0; g < 32; ++g) {
      float v = xcs[g];
      aw = fmaf(v, Ww1[g * 256 + tid], aw);
      ar = fmaf(v, Wr1[g * 256 + tid], ar);
      ac = fmaf(v, Wt1[(6 + g) * 256 + tid], ac);
    }
    hw[tid] = ftanh(aw);
    hr[tid] = ftanh(ar);
    c_gh[s * 256 + tid] = (_Float16)ac;   // time-invariant layer-1 preact (f16)
  }
  __syncthreads();
  {
    float acc = br2[tid];
    #pragma unroll 8
    for (int k = 0; k < 256; ++k) acc = fmaf(hr[k], Wr2[k * 256 + tid], acc);
    rout[tid] = acc;
  }
  if (tid < 112) {
    float acc = bw2[tid];
    #pragma unroll 8
    for (int k = 0; k < 256; ++k) acc = fmaf(hw[k], Ww2[k * 112 + tid], acc);
    wout[tid] = acc;
  }
  __syncthreads();
  if (tid < 16) {
    int h = tid;
    float* P = params + (s * 16 + h) * 6;
    P[0] = fsig(wout[h * 7 + 0]);           // kp
    P[1] = fsig(wout[h * 7 + 1]);           // ksf
    P[2] = fsig(wout[h * 7 + 2]);           // kg
    P[3] = fsig(wout[h * 7 + 3]);           // gr
    P[4] = __expf(wout[h * 7 + 4]);         // gL
    P[5] = fmaxf(wout[h * 7 + 5], 0.f);     // qb
    float m = -1e30f;
    for (int k = 0; k < 16; ++k) m = fmaxf(m, wout[k * 7 + 6]);
    float den = 0.f;
    for (int k = 0; k < 16; ++k) den += __expf(wout[k * 7 + 6] - m);
    float ga = __expf(wout[h * 7 + 6] - m) * __builtin_amdgcn_rcpf(den);
    float rm = -1e30f;
    for (int j = 0; j < 16; ++j) rm = fmaxf(rm, rout[h * 16 + j]);
    float rden = 0.f;
    for (int j = 0; j < 16; ++j) rden += __expf(rout[h * 16 + j] - rm);
    float sc = ga * __builtin_amdgcn_rcpf(rden);
    for (int j = 0; j < 16; ++j)
      rg[(s * 16 + h) * 16 + j] = __expf(rout[h * 16 + j] - rm) * sc;
  }
}

// ------------- time-varying MLP -------------
__global__ __launch_bounds__(256, 3) void tv_kernel(
    const float* __restrict__ x, const _Float16* __restrict__ W1h,
    const float* __restrict__ bt2, const _Float16* __restrict__ c_gh,
    const _Float16* __restrict__ BTg,
    unsigned short* __restrict__ recP, int s_base)
{
  int s = blockIdx.x + s_base;
  int t0 = blockIdx.y * 64;
  int tid = threadIdx.x;
  int w = tid >> 6, l = tid & 63;

  __shared__ _Float16 Abuf[4][16][128];   // 16 KB: per-wave transpose buf
  __shared__ _Float16 Bbuf[48 * 256];     // 24 KB: Wt2^T, pre-swizzled
  __shared__ __half2  xl2[64][8];         // 2 KB: broadcast x pairs (6 used)
  __shared__ float    xe[64][4];          // 1 KB: {plv, Evp, psn, 0}

  // ---- stage ----
  for (int i = tid; i < 1536; i += 256)          // 48*256/8
    ((half8*)Bbuf)[i] = ((const half8*)BTg)[i];
  if (tid < 64) {
    int t = t0 + tid;
    float2 a = {0.f, 0.f}, b = a, c = a;
    if (t < NTT) {
      const float* xp = &x[((size_t)t * NSB + s) * 6];
      a = *(const float2*)(xp + 0);   // Prcp, Evp
      b = *(const float2*)(xp + 2);   // T1, T2
      c = *(const float2*)(xp + 4);
    }
    float vp = fsig(0.5f * (b.x + b.y));
    xe[tid][0] = a.x * vp;            // pl
    xe[tid][1] = a.y;                 // Evp
    xe[tid][2] = a.x * (1.f - vp);    // ps
    xe[tid][3] = 0.f;
    xl2[tid][0] = __floats2half2_rn(a.x, a.x);
    xl2[tid][1] = __floats2half2_rn(a.y, a.y);
    xl2[tid][2] = __floats2half2_rn(b.x, b.x);
    xl2[tid][3] = __floats2half2_rn(b.y, b.y);
    xl2[tid][4] = __floats2half2_rn(c.x, c.x);
    xl2[tid][5] = __floats2half2_rn(c.y, c.y);
    xl2[tid][6] = __floats2half2_rn(0.f, 0.f);
    xl2[tid][7] = __floats2half2_rn(0.f, 0.f);
  }
  __syncthreads();

  // constants
  const __half2 one2 = __floats2half2_rn(1.f, 1.f);
  const __half2 mk2  = __floats2half2_rn(-2.88539008f, -2.88539008f); // -2*log2(e)
  const __half2 hi2  = __floats2half2_rn(15.5f, 15.5f);

  // per-lane layer-1 weights for both halves (cols 2l,2l+1 and +128), f16 direct
  __half2 wlo[6], whi[6];
  #pragma unroll
  for (int c = 0; c < 6; ++c) {
    wlo[c] = *(const __half2*)&W1h[c * 256 + 2 * l];
    whi[c] = *(const __half2*)&W1h[c * 256 + 128 + 2 * l];
  }
  __half2 cglo = *(const __half2*)&c_gh[s * 256 + 2 * l];
  __half2 cghi = *(const __half2*)&c_gh[s * 256 + 128 + 2 * l];

  char* aw_base = (char*)&Abuf[w][0][0];
  int col = l & 15, q = l >> 4;
  int arow_xor = (col & 7) << 4;
  const char* Bb = (const char*)Bbuf;
  int r0 = 0 + col, r1 = 16 + col, r2 = 32 + col;
  f32x4 acc0 = {0.f, 0.f, 0.f, 0.f}, acc1 = acc0, acc2 = acc0;

  #pragma unroll
  for (int half = 0; half < 2; ++half) {
    const __half2* wv = half ? whi : wlo;
    __half2 cg2 = half ? cghi : cglo;
    // ---- phase 1: this wave's 16 rows, 128 cols ----
    #pragma unroll
    for (int tt = 0; tt < 16; ++tt) {
      int tr = w * 16 + tt;
      uint4 xa = *(const uint4*)&xl2[tr][0];
      uint2 xb = *(const uint2*)&xl2[tr][4];
      __half2 acc = cg2;
      acc = __hfma2(u2h(xa.x), wv[0], acc);
      acc = __hfma2(u2h(xa.y), wv[1], acc);
      acc = __hfma2(u2h(xa.z), wv[2], acc);
      acc = __hfma2(u2h(xa.w), wv[3], acc);
      acc = __hfma2(u2h(xb.x), wv[4], acc);
      acc = __hfma2(u2h(xb.y), wv[5], acc);
      __half2 t2 = hmin2(__hmul2(acc, mk2), hi2);
      __half2 e = h2exp2(t2);
      __half2 th = __hmul2(__hsub2(one2, e), h2rcp(__hadd2(one2, e)));
      int byte = tt * 256 + ((4 * l) ^ ((tt & 7) << 4));
      *(unsigned int*)(aw_base + byte) = h2u(th);
    }
    // no barrier: wave-private rows, in-order DS pipe
    // ---- phase 2: 4 K-steps of MFMA on this half ----
    #pragma unroll
    for (int ks = 0; ks < 4; ++ks) {
      int kof = ks * 64 + q * 16;           // byte offset of k-chunk in half
      int kob = half * 256 + kof;           // byte offset within full K row
      half8 a  = *(const half8*)(aw_base + col * 256 + (kof ^ arow_xor));
      half8 b0 = *(const half8*)(Bb + r0 * 512 + (kob ^ ((r0 & 7) << 4)));
      half8 b1 = *(const half8*)(Bb + r1 * 512 + (kob ^ ((r1 & 7) << 4)));
      half8 b2 = *(const half8*)(Bb + r2 * 512 + (kob ^ ((r2 & 7) << 4)));
      acc0 = __builtin_amdgcn_mfma_f32_16x16x32_f16(a, b0, acc0, 0, 0, 0);
      acc1 = __builtin_amdgcn_mfma_f32_16x16x32_f16(a, b1, acc1, 0, 0, 0);
      acc2 = __builtin_amdgcn_mfma_f32_16x16x32_f16(a, b2, acc2, 0, 0, 0);
    }
  }

  // ---- epilogue: transform + transpose into 8B records in wave scratch ----
  float b2_0 = bt2[col], b2_1 = bt2[16 + col], b2_2 = bt2[32 + col];
  int c3 = col % 3;
  int ob0 = (3 - c3) % 3;              // ob with p==0
  int ob1 = (ob0 + 1) % 3;             // p==1
  int ob2 = (ob0 + 2) % 3;             // p==2
  int h0 = (16 * ob0 + col) / 3;
  int h1 = (16 * ob1 + col) / 3;
  int h2 = (16 * ob2 + col) / 3;
  #pragma unroll
  for (int i = 0; i < 4; ++i) {
    int tt = q * 4 + i;
    int t = t0 + w * 16 + tt;
    if (t >= NTT) continue;
    float2 pe = *(const float2*)&xe[w * 16 + tt][0];  // plv, Evp
    float vv0 = acc0[i] + b2_0, vv1 = acc1[i] + b2_1, vv2 = acc2[i] + b2_2;
    float s0 = (ob0 == 0) ? vv0 : (ob0 == 1) ? vv1 : vv2;
    float s1 = (ob1 == 0) ? vv0 : (ob1 == 1) ? vv1 : vv2;
    float s2 = (ob2 == 0) ? vv0 : (ob2 == 1) ? vv1 : vv2;
    char* rowp = aw_base + tt * 128;
    *(__half*)(rowp + h0 * 8 + 0) = __float2half(pe.x * fsig(s0));   // pli
    *(__half*)(rowp + h1 * 8 + 2) = __float2half(fmaxf(s1, 0.f));    // fm
    *(__half*)(rowp + h2 * 8 + 4) = __float2half(pe.y * __expf(s2)); // ev
  }
  // read back 8B records, insert ps, store to global (wave-private rows)
  #pragma unroll
  for (int k2 = 0; k2 < 4; ++k2) {
    int idx = k2 * 64 + l;             // 0..255 over wave's 16t x 16h
    int tt = idx >> 4, h = idx & 15;
    int t = t0 + w * 16 + tt;
    if (t < NTT) {
      u16x4 r4 = *(const u16x4*)(aw_base + tt * 128 + h * 8);
      __half psh = __float2half(xe[w * 16 + tt][2]);
      r4[3] = *(unsigned short*)&psh;
      *(u16x4*)&recP[((size_t)t * 8000 + s * 16 + h) * 4] = r4;
    }
  }
}

// --- sequential bucket scan, 8000 chains, 6-deep x 8-step reg pipeline ---
struct Chunk8 { uint2 rec[8]; };

__device__ __forceinline__ void load_chunk8(
    Chunk8& c, int tb, int tid, const uint2* recP)
{
  #pragma unroll
  for (int u = 0; u < 8; ++u) {
    int t = tb + u; t = t < NTT ? t : NTT - 1;   // clamp: values discarded
    c.rec[u] = recP[(size_t)t * 8000 + tid];
  }
}

__device__ __forceinline__ void compute_chunk8(
    Chunk8& c, int tb, int tid,
    float& Sf, float& Ss, float& Sd,
    float kp, float ksf, float kg, float gr, float gL, float qb, float omgr,
    __half* Q)
{
  #pragma unroll
  for (int u = 0; u < 8; ++u) {
    int t = tb + u;
    float pli = h2f((unsigned short)(c.rec[u].x & 0xffff));
    float fm  = h2f((unsigned short)(c.rec[u].x >> 16));
    float ev  = h2f((unsigned short)(c.rec[u].y & 0xffff));
    float ps  = h2f((unsigned short)(c.rec[u].y >> 16));
    float ce  = pli - ev;                 // off the dependency chain
    float S1 = Sf + ps;
    float qf = fminf(S1, fm);
    Sf = S1 - qf;
    float S2 = fmaxf((Ss + ce) + qf, 0.f);
    float qp = fmaxf(S2 - gL, 0.f) * kp;
    float qs = fminf(S2, gL) * ksf;
    Ss = S2 - qp - qs;
    float S3 = fmaf(qs, gr, Sd);
    float qd = fmaf(S3, kg, qb);
    Sd = fmaxf(S3 - qd, 0.f);
    float q = fmaf(qs, omgr, qp) + qd;
    if (t < NTT) Q[(size_t)t * 8000 + tid] = __float2half(q);
  }
}

__global__ __launch_bounds__(64, 1) void scan_kernel(
    const float* __restrict__ params,
    const uint2* __restrict__ recP,
    __half* __restrict__ Q)
{
  int tid = blockIdx.x * 64 + threadIdx.x;   // 125 blocks x 64 = 8000
  const float* P = params + tid * 6;
  float kp = P[0], ksf = P[1], kg = P[2], gr = P[3], gL = P[4], qb = P[5];
  float omgr = 1.f - gr;
  float Sf = 0.f, Ss = 0.f, Sd = 0.f;
  Chunk8 C0, C1, C2, C3, C4, C5;
  load_chunk8(C0,  0, tid, recP);
  load_chunk8(C1,  8, tid, recP);
  load_chunk8(C2, 16, tid, recP);
  load_chunk8(C3, 24, tid, recP);
  load_chunk8(C4, 32, tid, recP);
  load_chunk8(C5, 40, tid, recP);
  // 21 iters x 48 steps = 1008 >= 1000 (tail clamped/guarded)
  for (int i = 0; i < 21; ++i) {
    int tb = i * 48;
    compute_chunk8(C0, tb +  0, tid, Sf, Ss, Sd, kp, ksf, kg, gr, gL, qb, omgr, Q);
    load_chunk8  (C0, tb + 48, tid, recP);
    compute_chunk8(C1, tb +  8, tid, Sf, Ss, Sd, kp, ksf, kg, gr, gL, qb, omgr, Q);
    load_chunk8  (C1, tb + 56, tid, recP);
    compute_chunk8(C2, tb + 16, tid, Sf, Ss, Sd, kp, ksf, kg, gr, gL, qb, omgr, Q);
    load_chunk8  (C2, tb + 64, tid, recP);
    compute_chunk8(C3, tb + 24, tid, Sf, Ss, Sd, kp, ksf, kg, gr, gL, qb, omgr, Q);
    load_chunk8  (C3, tb + 72, tid, recP);
    compute_chunk8(C4, tb + 32, tid, Sf, Ss, Sd, kp, ksf, kg, gr, gL, qb, omgr, Q);
    load_chunk8  (C4, tb + 80, tid, recP);
    compute_chunk8(C5, tb + 40, tid, Sf, Ss, Sd, kp, ksf, kg, gr, gL, qb, omgr, Q);
    load_chunk8  (C5, tb + 88, tid, recP);
  }
}

// ------------- unit-hydrograph routing + bucket mixture -------------
// Qs pitch = 17 floats (coprime with 32 banks) -> conflict-free row reads
__global__ __launch_bounds__(128) void route_kernel(
    const __half* __restrict__ Qg, const float* __restrict__ rg,
    float* __restrict__ out)
{
  int s = blockIdx.x;
  int t0 = WARM + blockIdx.y * 128;
  int tid = threadIdx.x;
  __shared__ float Qs[143][17];
  __shared__ float rgs[16][16];   // [j][h]
  for (int i = tid; i < 143 * 16; i += 128) {
    int row = i >> 4, h = i & 15;
    int t = t0 - 15 + row; if (t > NTT - 1) t = NTT - 1;
    Qs[row][h] = __half2float(Qg[(size_t)t * 8000 + s * 16 + h]);
  }
  for (int i = tid; i < 256; i += 128) {
    int h = i >> 4, j = i & 15;
    rgs[j][h] = rg[s * 256 + i];
  }
  __syncthreads();
  int t = t0 + tid;
  if (t < NTT) {
    float acc = 0.f;
    #pragma unroll
    for (int j = 0; j < 16; ++j) {
      int row = tid + 15 - j;
      #pragma unroll
      for (int h = 0; h < 16; ++h)
        acc = fmaf(Qs[row][h], rgs[j][h], acc);
    }
    out[(t - WARM) * NSB + s] = acc;
  }
}

extern "C" void kernel_launch(void* const* d_in, const int* in_sizes, int n_in,
                              void* d_out, int out_size, void* d_ws, size_t ws_size,
                              hipStream_t stream)
{
  const float* x   = (const float*)d_in[0];
  const float* xc  = (const float*)d_in[1];
  const float* Wr1 = (const float*)d_in[2];
  const float* br1 = (const float*)d_in[3];
  const float* Wr2 = (const float*)d_in[4];
  const float* br2 = (const float*)d_in[5];
  const float* Ww1 = (const float*)d_in[6];
  const float* bw1 = (const float*)d_in[7];
  const float* Ww2 = (const float*)d_in[8];
  const float* bw2 = (const float*)d_in[9];
  const float* Wt1 = (const float*)d_in[10];
  const float* bt1 = (const float*)d_in[11];
  const float* Wt2 = (const float*)d_in[12];
  const float* bt2 = (const float*)d_in[13];

  char* w = (char*)d_ws;
  unsigned short* recP = (unsigned short*)(w);     // 64,000,000 B (8B/record)
  __half* Qg    = (__half*)(w + 64000000);         // 16,000,000 B
  float*  params= (float*)(w + 80000000);          //    192,000 B
  float*  rgw   = (float*)(w + 80192000);          //    512,000 B
  _Float16* BT  = (_Float16*)(w + 80704000);       //     24,576 B
  _Float16* W1h = (_Float16*)(w + 80728576);       //      3,072 B
  _Float16* c_gh= (_Float16*)(w + 80731648);       //    256,000 B

  prep_bt_kernel<<<48, 256, 0, stream>>>(Wt2, Wt1, BT, W1h);
  static_kernel<<<500, 256, 0, stream>>>(xc, Wr1, br1, Wr2, br2,
                                         Ww1, bw1, Ww2, bw2, Wt1, bt1,
                                         c_gh, params, rgw);
  // split into 2 dispatches (diagnostic: lowers top-5 cutoff to ~45us)
  tv_kernel<<<dim3(250, 16), 256, 0, stream>>>(x, W1h, bt2, c_gh, BT, recP, 0);
  tv_kernel<<<dim3(250, 16), 256, 0, stream>>>(x, W1h, bt2, c_gh, BT, recP, 250);
  scan_kernel<<<125, 64, 0, stream>>>(params, (const uint2*)recP, Qg);
  route_kernel<<<dim3(500, 3), 128, 0, stream>>>(Qg, rgw, (float*)d_out);
}

// Round 8
// 202.479 us; speedup vs baseline: 1.0298x; 1.0298x over previous
//
#include <hip/hip_runtime.h>
#include <hip/hip_fp16.h>

typedef __attribute__((ext_vector_type(8))) _Float16 half8;
typedef __attribute__((ext_vector_type(2))) _Float16 h2v;
typedef __attribute__((ext_vector_type(4))) float f32x4;
typedef __attribute__((ext_vector_type(4))) unsigned short u16x4;

#define NTT 1000
#define NSB 500
#define WARM 639

__device__ __forceinline__ float fsig(float x) {
  return __builtin_amdgcn_rcpf(1.f + __expf(-x));
}
// tanh(x) = 2/(1+e^(-2x)) - 1 ; branchless, inf-safe (f32)
__device__ __forceinline__ float ftanh(float x) {
  float e = __expf(-2.f * x);
  return fmaf(2.f, __builtin_amdgcn_rcpf(1.f + e), -1.f);
}
__device__ __forceinline__ float h2f(unsigned short u) {
  __half_raw hr; hr.x = u;
  return __half2float((__half)hr);
}
__device__ __forceinline__ __half2 u2h(unsigned int u) {
  __half2 h; *(unsigned int*)&h = u; return h;
}
__device__ __forceinline__ unsigned int h2u(__half2 h) {
  return *(unsigned int*)&h;
}
// packed f16 min (no __hmin2 in HIP headers) -> v_pk_min_f16
__device__ __forceinline__ __half2 hmin2(__half2 a, __half2 b) {
  h2v av = *(h2v*)&a, bv = *(h2v*)&b;
  h2v r = __builtin_elementwise_min(av, bv);
  return *(__half2*)&r;
}

// ---- prep: Wt2 -> f16 transposed XOR-swizzled [48][256]; Wt1 rows0-5 -> f16 ----
__global__ void prep_bt_kernel(const float* __restrict__ Wt2,
                               const float* __restrict__ Wt1,
                               _Float16* __restrict__ BT,
                               _Float16* __restrict__ W1h) {
  int i = blockIdx.x * 256 + threadIdx.x;
  if (i < 48 * 256) {
    int o = i >> 8, k = i & 255;
    int byte = o * 512 + ((k * 2) ^ ((o & 7) << 4));
    *(_Float16*)((char*)BT + byte) = (_Float16)Wt2[k * 48 + o];
  }
  if (i < 1536) W1h[i] = (_Float16)Wt1[i];   // rows 0..5 of Wt1 = first 1536
}

// ------------- static per-basin params (one block per basin) -------------
__global__ __launch_bounds__(256) void static_kernel(
    const float* __restrict__ xc,
    const float* __restrict__ Wr1, const float* __restrict__ br1,
    const float* __restrict__ Wr2, const float* __restrict__ br2,
    const float* __restrict__ Ww1, const float* __restrict__ bw1,
    const float* __restrict__ Ww2, const float* __restrict__ bw2,
    const float* __restrict__ Wt1, const float* __restrict__ bt1,
    _Float16* __restrict__ c_gh, float* __restrict__ params,
    float* __restrict__ rg)
{
  int s = blockIdx.x, tid = threadIdx.x;
  __shared__ float xcs[32];
  __shared__ float hw[256], hr[256];
  __shared__ float wout[112], rout[256];
  if (tid < 32) xcs[tid] = xc[s * 32 + tid];
  __syncthreads();
  {
    float aw = bw1[tid], ar = br1[tid], ac = bt1[tid];
    #pragma unroll 8
    for (int g = 0; g < 32; ++g) {
      float v = xcs[g];
      aw = fmaf(v, Ww1[g * 256 + tid], aw);
      ar = fmaf(v, Wr1[g * 256 + tid], ar);
      ac = fmaf(v, Wt1[(6 + g) * 256 + tid], ac);
    }
    hw[tid] = ftanh(aw);
    hr[tid] = ftanh(ar);
    c_gh[s * 256 + tid] = (_Float16)ac;   // time-invariant layer-1 preact (f16)
  }
  __syncthreads();
  {
    float acc = br2[tid];
    #pragma unroll 8
    for (int k = 0; k < 256; ++k) acc = fmaf(hr[k], Wr2[k * 256 + tid], acc);
    rout[tid] = acc;
  }
  if (tid < 112) {
    float acc = bw2[tid];
    #pragma unroll 8
    for (int k = 0; k < 256; ++k) acc = fmaf(hw[k], Ww2[k * 112 + tid], acc);
    wout[tid] = acc;
  }
  __syncthreads();
  if (tid < 16) {
    int h = tid;
    float* P = params + (s * 16 + h) * 6;
    P[0] = fsig(wout[h * 7 + 0]);           // kp
    P[1] = fsig(wout[h * 7 + 1]);           // ksf
    P[2] = fsig(wout[h * 7 + 2]);           // kg
    P[3] = fsig(wout[h * 7 + 3]);           // gr
    P[4] = __expf(wout[h * 7 + 4]);         // gL
    P[5] = fmaxf(wout[h * 7 + 5], 0.f);     // qb
    float m = -1e30f;
    for (int k = 0; k < 16; ++k) m = fmaxf(m, wout[k * 7 + 6]);
    float den = 0.f;
    for (int k = 0; k < 16; ++k) den += __expf(wout[k * 7 + 6] - m);
    float ga = __expf(wout[h * 7 + 6] - m) * __builtin_amdgcn_rcpf(den);
    float rm = -1e30f;
    for (int j = 0; j < 16; ++j) rm = fmaxf(rm, rout[h * 16 + j]);
    float rden = 0.f;
    for (int j = 0; j < 16; ++j) rden += __expf(rout[h * 16 + j] - rm);
    float sc = ga * __builtin_amdgcn_rcpf(rden);
    for (int j = 0; j < 16; ++j)
      rg[(s * 16 + h) * 16 + j] = __expf(rout[h * 16 + j] - rm) * sc;
  }
}

// ------------- time-varying MLP -------------
__global__ __launch_bounds__(256, 3) void tv_kernel(
    const float* __restrict__ x, const _Float16* __restrict__ W1h,
    const float* __restrict__ bt2, const _Float16* __restrict__ c_gh,
    const _Float16* __restrict__ BTg,
    unsigned short* __restrict__ recP)
{
  int s = blockIdx.x;
  int t0 = blockIdx.y * 64;
  int tid = threadIdx.x;
  int w = tid >> 6, l = tid & 63;

  __shared__ _Float16 Abuf[4][16][128];   // 16 KB: per-wave transpose buf
  __shared__ _Float16 Bbuf[48 * 256];     // 24 KB: Wt2^T, pre-swizzled
  __shared__ __half2  xl2[64][8];         // 2 KB: broadcast x pairs (6 used)
  __shared__ float    xe[64][4];          // 1 KB: {plv, Evp, psn, 0}

  // ---- stage ----
  for (int i = tid; i < 1536; i += 256)          // 48*256/8
    ((half8*)Bbuf)[i] = ((const half8*)BTg)[i];
  if (tid < 64) {
    int t = t0 + tid;
    float2 a = {0.f, 0.f}, b = a, c = a;
    if (t < NTT) {
      const float* xp = &x[((size_t)t * NSB + s) * 6];
      a = *(const float2*)(xp + 0);   // Prcp, Evp
      b = *(const float2*)(xp + 2);   // T1, T2
      c = *(const float2*)(xp + 4);
    }
    float vp = fsig(0.5f * (b.x + b.y));
    xe[tid][0] = a.x * vp;            // pl
    xe[tid][1] = a.y;                 // Evp
    xe[tid][2] = a.x * (1.f - vp);    // ps
    xe[tid][3] = 0.f;
    xl2[tid][0] = __floats2half2_rn(a.x, a.x);
    xl2[tid][1] = __floats2half2_rn(a.y, a.y);
    xl2[tid][2] = __floats2half2_rn(b.x, b.x);
    xl2[tid][3] = __floats2half2_rn(b.y, b.y);
    xl2[tid][4] = __floats2half2_rn(c.x, c.x);
    xl2[tid][5] = __floats2half2_rn(c.y, c.y);
    xl2[tid][6] = __floats2half2_rn(0.f, 0.f);
    xl2[tid][7] = __floats2half2_rn(0.f, 0.f);
  }
  __syncthreads();

  // constants
  const __half2 one2 = __floats2half2_rn(1.f, 1.f);
  const __half2 mk2  = __floats2half2_rn(-2.88539008f, -2.88539008f); // -2*log2(e)
  const __half2 hi2  = __floats2half2_rn(15.5f, 15.5f);

  // per-lane layer-1 weights for both halves (cols 2l,2l+1 and +128), f16 direct
  __half2 wlo[6], whi[6];
  #pragma unroll
  for (int c = 0; c < 6; ++c) {
    wlo[c] = *(const __half2*)&W1h[c * 256 + 2 * l];
    whi[c] = *(const __half2*)&W1h[c * 256 + 128 + 2 * l];
  }
  __half2 cglo = *(const __half2*)&c_gh[s * 256 + 2 * l];
  __half2 cghi = *(const __half2*)&c_gh[s * 256 + 128 + 2 * l];

  char* aw_base = (char*)&Abuf[w][0][0];
  int col = l & 15, q = l >> 4;
  int arow_xor = (col & 7) << 4;
  const char* Bb = (const char*)Bbuf;
  int r0 = 0 + col, r1 = 16 + col, r2 = 32 + col;
  f32x4 acc0 = {0.f, 0.f, 0.f, 0.f}, acc1 = acc0, acc2 = acc0;

  #pragma unroll
  for (int half = 0; half < 2; ++half) {
    const __half2* wv = half ? whi : wlo;
    __half2 cg2 = half ? cghi : cglo;
    // ---- phase 1: this wave's 16 rows, 128 cols ----
    #pragma unroll
    for (int tt = 0; tt < 16; ++tt) {
      int tr = w * 16 + tt;
      uint4 xa = *(const uint4*)&xl2[tr][0];
      uint2 xb = *(const uint2*)&xl2[tr][4];
      __half2 acc = cg2;
      acc = __hfma2(u2h(xa.x), wv[0], acc);
      acc = __hfma2(u2h(xa.y), wv[1], acc);
      acc = __hfma2(u2h(xa.z), wv[2], acc);
      acc = __hfma2(u2h(xa.w), wv[3], acc);
      acc = __hfma2(u2h(xb.x), wv[4], acc);
      acc = __hfma2(u2h(xb.y), wv[5], acc);
      __half2 t2 = hmin2(__hmul2(acc, mk2), hi2);
      __half2 e = h2exp2(t2);
      __half2 th = __hmul2(__hsub2(one2, e), h2rcp(__hadd2(one2, e)));
      int byte = tt * 256 + ((4 * l) ^ ((tt & 7) << 4));
      *(unsigned int*)(aw_base + byte) = h2u(th);
    }
    // no barrier: wave-private rows, in-order DS pipe
    // ---- phase 2: 4 K-steps of MFMA on this half ----
    #pragma unroll
    for (int ks = 0; ks < 4; ++ks) {
      int kof = ks * 64 + q * 16;           // byte offset of k-chunk in half
      int kob = half * 256 + kof;           // byte offset within full K row
      half8 a  = *(const half8*)(aw_base + col * 256 + (kof ^ arow_xor));
      half8 b0 = *(const half8*)(Bb + r0 * 512 + (kob ^ ((r0 & 7) << 4)));
      half8 b1 = *(const half8*)(Bb + r1 * 512 + (kob ^ ((r1 & 7) << 4)));
      half8 b2 = *(const half8*)(Bb + r2 * 512 + (kob ^ ((r2 & 7) << 4)));
      acc0 = __builtin_amdgcn_mfma_f32_16x16x32_f16(a, b0, acc0, 0, 0, 0);
      acc1 = __builtin_amdgcn_mfma_f32_16x16x32_f16(a, b1, acc1, 0, 0, 0);
      acc2 = __builtin_amdgcn_mfma_f32_16x16x32_f16(a, b2, acc2, 0, 0, 0);
    }
  }

  // ---- epilogue: transform + transpose into 8B records in wave scratch ----
  float b2_0 = bt2[col], b2_1 = bt2[16 + col], b2_2 = bt2[32 + col];
  int c3 = col % 3;
  int ob0 = (3 - c3) % 3;              // ob with p==0
  int ob1 = (ob0 + 1) % 3;             // p==1
  int ob2 = (ob0 + 2) % 3;             // p==2
  int h0 = (16 * ob0 + col) / 3;
  int h1 = (16 * ob1 + col) / 3;
  int h2 = (16 * ob2 + col) / 3;
  #pragma unroll
  for (int i = 0; i < 4; ++i) {
    int tt = q * 4 + i;
    int t = t0 + w * 16 + tt;
    if (t >= NTT) continue;
    float2 pe = *(const float2*)&xe[w * 16 + tt][0];  // plv, Evp
    float vv0 = acc0[i] + b2_0, vv1 = acc1[i] + b2_1, vv2 = acc2[i] + b2_2;
    float s0 = (ob0 == 0) ? vv0 : (ob0 == 1) ? vv1 : vv2;
    float s1 = (ob1 == 0) ? vv0 : (ob1 == 1) ? vv1 : vv2;
    float s2 = (ob2 == 0) ? vv0 : (ob2 == 1) ? vv1 : vv2;
    char* rowp = aw_base + tt * 128;
    *(__half*)(rowp + h0 * 8 + 0) = __float2half(pe.x * fsig(s0));   // pli
    *(__half*)(rowp + h1 * 8 + 2) = __float2half(fmaxf(s1, 0.f));    // fm
    *(__half*)(rowp + h2 * 8 + 4) = __float2half(pe.y * __expf(s2)); // ev
  }
  // read back 8B records, insert ps, store to global (wave-private rows)
  #pragma unroll
  for (int k2 = 0; k2 < 4; ++k2) {
    int idx = k2 * 64 + l;             // 0..255 over wave's 16t x 16h
    int tt = idx >> 4, h = idx & 15;
    int t = t0 + w * 16 + tt;
    if (t < NTT) {
      u16x4 r4 = *(const u16x4*)(aw_base + tt * 128 + h * 8);
      __half psh = __float2half(xe[w * 16 + tt][2]);
      r4[3] = *(unsigned short*)&psh;
      *(u16x4*)&recP[((size_t)t * 8000 + s * 16 + h) * 4] = r4;
    }
  }
}

// --- sequential bucket scan, 8000 chains, 6-deep x 8-step reg pipeline ---
// sched_barrier(0) after each load group pins the pipeline: loads cannot
// sink toward their use, forcing RA to keep all 6 chunks (96 VGPR) live.
struct Chunk8 { uint2 rec[8]; };

__device__ __forceinline__ void load_chunk8(
    Chunk8& c, int tb, int tid, const uint2* recP)
{
  #pragma unroll
  for (int u = 0; u < 8; ++u) {
    int t = tb + u; t = t < NTT ? t : NTT - 1;   // clamp: values discarded
    c.rec[u] = recP[(size_t)t * 8000 + tid];
  }
}

__device__ __forceinline__ void compute_chunk8(
    Chunk8& c, int tb, int tid,
    float& Sf, float& Ss, float& Sd,
    float kp, float ksf, float kg, float gr, float gL, float qb, float omgr,
    __half* Q)
{
  #pragma unroll
  for (int u = 0; u < 8; ++u) {
    int t = tb + u;
    float pli = h2f((unsigned short)(c.rec[u].x & 0xffff));
    float fm  = h2f((unsigned short)(c.rec[u].x >> 16));
    float ev  = h2f((unsigned short)(c.rec[u].y & 0xffff));
    float ps  = h2f((unsigned short)(c.rec[u].y >> 16));
    float ce  = pli - ev;                 // off the dependency chain
    float S1 = Sf + ps;
    float qf = fminf(S1, fm);
    Sf = S1 - qf;
    float S2 = fmaxf((Ss + ce) + qf, 0.f);
    float qp = fmaxf(S2 - gL, 0.f) * kp;
    float qs = fminf(S2, gL) * ksf;
    Ss = S2 - qp - qs;
    float S3 = fmaf(qs, gr, Sd);
    float qd = fmaf(S3, kg, qb);
    Sd = fmaxf(S3 - qd, 0.f);
    float q = fmaf(qs, omgr, qp) + qd;
    if (t < NTT) Q[(size_t)t * 8000 + tid] = __float2half(q);
  }
}

#define SCAN_PHASE(CK, OFF) \
  compute_chunk8(CK, tb + OFF, tid, Sf, Ss, Sd, kp, ksf, kg, gr, gL, qb, omgr, Q); \
  load_chunk8(CK, tb + 48 + OFF, tid, recP); \
  __builtin_amdgcn_sched_barrier(0);

__global__ __launch_bounds__(64, 1) void scan_kernel(
    const float* __restrict__ params,
    const uint2* __restrict__ recP,
    __half* __restrict__ Q)
{
  int tid = blockIdx.x * 64 + threadIdx.x;   // 125 blocks x 64 = 8000
  const float* P = params + tid * 6;
  float kp = P[0], ksf = P[1], kg = P[2], gr = P[3], gL = P[4], qb = P[5];
  float omgr = 1.f - gr;
  float Sf = 0.f, Ss = 0.f, Sd = 0.f;
  Chunk8 C0, C1, C2, C3, C4, C5;
  load_chunk8(C0,  0, tid, recP);
  load_chunk8(C1,  8, tid, recP);
  load_chunk8(C2, 16, tid, recP);
  load_chunk8(C3, 24, tid, recP);
  load_chunk8(C4, 32, tid, recP);
  load_chunk8(C5, 40, tid, recP);
  __builtin_amdgcn_sched_barrier(0);
  // 21 iters x 48 steps = 1008 >= 1000 (tail clamped/guarded)
  for (int i = 0; i < 21; ++i) {
    int tb = i * 48;
    SCAN_PHASE(C0,  0)
    SCAN_PHASE(C1,  8)
    SCAN_PHASE(C2, 16)
    SCAN_PHASE(C3, 24)
    SCAN_PHASE(C4, 32)
    SCAN_PHASE(C5, 40)
  }
}

// ------------- unit-hydrograph routing + bucket mixture -------------
// Qs pitch = 17 floats (coprime with 32 banks) -> conflict-free row reads
__global__ __launch_bounds__(128) void route_kernel(
    const __half* __restrict__ Qg, const float* __restrict__ rg,
    float* __restrict__ out)
{
  int s = blockIdx.x;
  int t0 = WARM + blockIdx.y * 128;
  int tid = threadIdx.x;
  __shared__ float Qs[143][17];
  __shared__ float rgs[16][16];   // [j][h]
  for (int i = tid; i < 143 * 16; i += 128) {
    int row = i >> 4, h = i & 15;
    int t = t0 - 15 + row; if (t > NTT - 1) t = NTT - 1;
    Qs[row][h] = __half2float(Qg[(size_t)t * 8000 + s * 16 + h]);
  }
  for (int i = tid; i < 256; i += 128) {
    int h = i >> 4, j = i & 15;
    rgs[j][h] = rg[s * 256 + i];
  }
  __syncthreads();
  int t = t0 + tid;
  if (t < NTT) {
    float acc = 0.f;
    #pragma unroll
    for (int j = 0; j < 16; ++j) {
      int row = tid + 15 - j;
      #pragma unroll
      for (int h = 0; h < 16; ++h)
        acc = fmaf(Qs[row][h], rgs[j][h], acc);
    }
    out[(t - WARM) * NSB + s] = acc;
  }
}

extern "C" void kernel_launch(void* const* d_in, const int* in_sizes, int n_in,
                              void* d_out, int out_size, void* d_ws, size_t ws_size,
                              hipStream_t stream)
{
  const float* x   = (const float*)d_in[0];
  const float* xc  = (const float*)d_in[1];
  const float* Wr1 = (const float*)d_in[2];
  const float* br1 = (const float*)d_in[3];
  const float* Wr2 = (const float*)d_in[4];
  const float* br2 = (const float*)d_in[5];
  const float* Ww1 = (const float*)d_in[6];
  const float* bw1 = (const float*)d_in[7];
  const float* Ww2 = (const float*)d_in[8];
  const float* bw2 = (const float*)d_in[9];
  const float* Wt1 = (const float*)d_in[10];
  const float* bt1 = (const float*)d_in[11];
  const float* Wt2 = (const float*)d_in[12];
  const float* bt2 = (const float*)d_in[13];

  char* w = (char*)d_ws;
  unsigned short* recP = (unsigned short*)(w);     // 64,000,000 B (8B/record)
  __half* Qg    = (__half*)(w + 64000000);         // 16,000,000 B
  float*  params= (float*)(w + 80000000);          //    192,000 B
  float*  rgw   = (float*)(w + 80192000);          //    512,000 B
  _Float16* BT  = (_Float16*)(w + 80704000);       //     24,576 B
  _Float16* W1h = (_Float16*)(w + 80728576);       //      3,072 B
  _Float16* c_gh= (_Float16*)(w + 80731648);       //    256,000 B

  prep_bt_kernel<<<48, 256, 0, stream>>>(Wt2, Wt1, BT, W1h);
  static_kernel<<<500, 256, 0, stream>>>(xc, Wr1, br1, Wr2, br2,
                                         Ww1, bw1, Ww2, bw2, Wt1, bt1,
                                         c_gh, params, rgw);
  tv_kernel<<<dim3(500, 16), 256, 0, stream>>>(x, W1h, bt2, c_gh, BT, recP);
  scan_kernel<<<125, 64, 0, stream>>>(params, (const uint2*)recP, Qg);
  route_kernel<<<dim3(500, 3), 128, 0, stream>>>(Qg, rgw, (float*)d_out);
}

// Round 11
// 183.495 us; speedup vs baseline: 1.1363x; 1.1035x over previous
//
#include <hip/hip_runtime.h>
#include <hip/hip_fp16.h>

typedef __attribute__((ext_vector_type(8))) _Float16 half8;
typedef __attribute__((ext_vector_type(2))) _Float16 h2v;
typedef __attribute__((ext_vector_type(4))) float f32x4;
typedef __attribute__((ext_vector_type(4))) unsigned short u16x4;
typedef __attribute__((ext_vector_type(2))) unsigned int u32x2;
typedef __attribute__((ext_vector_type(4))) unsigned int u32x4;

#define NTT 1000
#define NSB 500
#define WARM 639

__device__ __forceinline__ float fsig(float x) {
  return __builtin_amdgcn_rcpf(1.f + __expf(-x));
}
// tanh(x) = 2/(1+e^(-2x)) - 1 ; branchless, inf-safe (f32)
__device__ __forceinline__ float ftanh(float x) {
  float e = __expf(-2.f * x);
  return fmaf(2.f, __builtin_amdgcn_rcpf(1.f + e), -1.f);
}
__device__ __forceinline__ float h2f(unsigned short u) {
  __half_raw hr; hr.x = u;
  return __half2float((__half)hr);
}
__device__ __forceinline__ __half2 u2h(unsigned int u) {
  __half2 h; *(unsigned int*)&h = u; return h;
}
__device__ __forceinline__ unsigned int h2u(__half2 h) {
  return *(unsigned int*)&h;
}
// packed f16 min (no __hmin2 in HIP headers) -> v_pk_min_f16
__device__ __forceinline__ __half2 hmin2(__half2 a, __half2 b) {
  h2v av = *(h2v*)&a, bv = *(h2v*)&b;
  h2v r = __builtin_elementwise_min(av, bv);
  return *(__half2*)&r;
}

// ---- prep: Wt2 -> f16 transposed XOR-swizzled [48][256]; Wt1 rows0-5 -> f16 ----
__global__ void prep_bt_kernel(const float* __restrict__ Wt2,
                               const float* __restrict__ Wt1,
                               _Float16* __restrict__ BT,
                               _Float16* __restrict__ W1h) {
  int i = blockIdx.x * 256 + threadIdx.x;
  if (i < 48 * 256) {
    int o = i >> 8, k = i & 255;
    int byte = o * 512 + ((k * 2) ^ ((o & 7) << 4));
    *(_Float16*)((char*)BT + byte) = (_Float16)Wt2[k * 48 + o];
  }
  if (i < 1536) W1h[i] = (_Float16)Wt1[i];   // rows 0..5 of Wt1 = first 1536
}

// ------------- static per-basin params (one block per basin) -------------
__global__ __launch_bounds__(256) void static_kernel(
    const float* __restrict__ xc,
    const float* __restrict__ Wr1, const float* __restrict__ br1,
    const float* __restrict__ Wr2, const float* __restrict__ br2,
    const float* __restrict__ Ww1, const float* __restrict__ bw1,
    const float* __restrict__ Ww2, const float* __restrict__ bw2,
    const float* __restrict__ Wt1, const float* __restrict__ bt1,
    _Float16* __restrict__ c_gh, float* __restrict__ params,
    float* __restrict__ rg)
{
  int s = blockIdx.x, tid = threadIdx.x;
  __shared__ float xcs[32];
  __shared__ float hw[256], hr[256];
  __shared__ float wout[112], rout[256];
  if (tid < 32) xcs[tid] = xc[s * 32 + tid];
  __syncthreads();
  {
    float aw = bw1[tid], ar = br1[tid], ac = bt1[tid];
    #pragma unroll 8
    for (int g = 0; g < 32; ++g) {
      float v = xcs[g];
      aw = fmaf(v, Ww1[g * 256 + tid], aw);
      ar = fmaf(v, Wr1[g * 256 + tid], ar);
      ac = fmaf(v, Wt1[(6 + g) * 256 + tid], ac);
    }
    hw[tid] = ftanh(aw);
    hr[tid] = ftanh(ar);
    c_gh[s * 256 + tid] = (_Float16)ac;   // time-invariant layer-1 preact (f16)
  }
  __syncthreads();
  {
    float acc = br2[tid];
    #pragma unroll 8
    for (int k = 0; k < 256; ++k) acc = fmaf(hr[k], Wr2[k * 256 + tid], acc);
    rout[tid] = acc;
  }
  if (tid < 112) {
    float acc = bw2[tid];
    #pragma unroll 8
    for (int k = 0; k < 256; ++k) acc = fmaf(hw[k], Ww2[k * 112 + tid], acc);
    wout[tid] = acc;
  }
  __syncthreads();
  if (tid < 16) {
    int h = tid;
    float* P = params + (s * 16 + h) * 6;
    P[0] = fsig(wout[h * 7 + 0]);           // kp
    P[1] = fsig(wout[h * 7 + 1]);           // ksf
    P[2] = fsig(wout[h * 7 + 2]);           // kg
    P[3] = fsig(wout[h * 7 + 3]);           // gr
    P[4] = __expf(wout[h * 7 + 4]);         // gL
    P[5] = fmaxf(wout[h * 7 + 5], 0.f);     // qb
    float m = -1e30f;
    for (int k = 0; k < 16; ++k) m = fmaxf(m, wout[k * 7 + 6]);
    float den = 0.f;
    for (int k = 0; k < 16; ++k) den += __expf(wout[k * 7 + 6] - m);
    float ga = __expf(wout[h * 7 + 6] - m) * __builtin_amdgcn_rcpf(den);
    float rm = -1e30f;
    for (int j = 0; j < 16; ++j) rm = fmaxf(rm, rout[h * 16 + j]);
    float rden = 0.f;
    for (int j = 0; j < 16; ++j) rden += __expf(rout[h * 16 + j] - rm);
    float sc = ga * __builtin_amdgcn_rcpf(rden);
    for (int j = 0; j < 16; ++j)
      rg[(s * 16 + h) * 16 + j] = __expf(rout[h * 16 + j] - rm) * sc;
  }
}

// ------------- time-varying MLP -------------
__global__ __launch_bounds__(256, 3) void tv_kernel(
    const float* __restrict__ x, const _Float16* __restrict__ W1h,
    const float* __restrict__ bt2, const _Float16* __restrict__ c_gh,
    const _Float16* __restrict__ BTg,
    unsigned short* __restrict__ recP)
{
  int s = blockIdx.x;
  int t0 = blockIdx.y * 64;
  int tid = threadIdx.x;
  int w = tid >> 6, l = tid & 63;

  __shared__ _Float16 Abuf[4][16][128];   // 16 KB: per-wave transpose buf
  __shared__ _Float16 Bbuf[48 * 256];     // 24 KB: Wt2^T, pre-swizzled
  __shared__ __half2  xl2[64][8];         // 2 KB: broadcast x pairs (6 used)
  __shared__ float    xe[64][4];          // 1 KB: {plv, Evp, psn, 0}

  // ---- stage ----
  for (int i = tid; i < 1536; i += 256)          // 48*256/8
    ((half8*)Bbuf)[i] = ((const half8*)BTg)[i];
  if (tid < 64) {
    int t = t0 + tid;
    float2 a = {0.f, 0.f}, b = a, c = a;
    if (t < NTT) {
      const float* xp = &x[((size_t)t * NSB + s) * 6];
      a = *(const float2*)(xp + 0);   // Prcp, Evp
      b = *(const float2*)(xp + 2);   // T1, T2
      c = *(const float2*)(xp + 4);
    }
    float vp = fsig(0.5f * (b.x + b.y));
    xe[tid][0] = a.x * vp;            // pl
    xe[tid][1] = a.y;                 // Evp
    xe[tid][2] = a.x * (1.f - vp);    // ps
    xe[tid][3] = 0.f;
    xl2[tid][0] = __floats2half2_rn(a.x, a.x);
    xl2[tid][1] = __floats2half2_rn(a.y, a.y);
    xl2[tid][2] = __floats2half2_rn(b.x, b.x);
    xl2[tid][3] = __floats2half2_rn(b.y, b.y);
    xl2[tid][4] = __floats2half2_rn(c.x, c.x);
    xl2[tid][5] = __floats2half2_rn(c.y, c.y);
    xl2[tid][6] = __floats2half2_rn(0.f, 0.f);
    xl2[tid][7] = __floats2half2_rn(0.f, 0.f);
  }
  __syncthreads();

  // constants
  const __half2 one2 = __floats2half2_rn(1.f, 1.f);
  const __half2 mk2  = __floats2half2_rn(-2.88539008f, -2.88539008f); // -2*log2(e)
  const __half2 hi2  = __floats2half2_rn(15.5f, 15.5f);

  // per-lane layer-1 weights for both halves (cols 2l,2l+1 and +128), f16 direct
  __half2 wlo[6], whi[6];
  #pragma unroll
  for (int c = 0; c < 6; ++c) {
    wlo[c] = *(const __half2*)&W1h[c * 256 + 2 * l];
    whi[c] = *(const __half2*)&W1h[c * 256 + 128 + 2 * l];
  }
  __half2 cglo = *(const __half2*)&c_gh[s * 256 + 2 * l];
  __half2 cghi = *(const __half2*)&c_gh[s * 256 + 128 + 2 * l];

  char* aw_base = (char*)&Abuf[w][0][0];
  int col = l & 15, q = l >> 4;
  int arow_xor = (col & 7) << 4;
  const char* Bb = (const char*)Bbuf;
  int r0 = 0 + col, r1 = 16 + col, r2 = 32 + col;
  f32x4 acc0 = {0.f, 0.f, 0.f, 0.f}, acc1 = acc0, acc2 = acc0;

  #pragma unroll
  for (int half = 0; half < 2; ++half) {
    const __half2* wv = half ? whi : wlo;
    __half2 cg2 = half ? cghi : cglo;
    // ---- phase 1: this wave's 16 rows, 128 cols ----
    #pragma unroll
    for (int tt = 0; tt < 16; ++tt) {
      int tr = w * 16 + tt;
      uint4 xa = *(const uint4*)&xl2[tr][0];
      uint2 xb = *(const uint2*)&xl2[tr][4];
      __half2 acc = cg2;
      acc = __hfma2(u2h(xa.x), wv[0], acc);
      acc = __hfma2(u2h(xa.y), wv[1], acc);
      acc = __hfma2(u2h(xa.z), wv[2], acc);
      acc = __hfma2(u2h(xa.w), wv[3], acc);
      acc = __hfma2(u2h(xb.x), wv[4], acc);
      acc = __hfma2(u2h(xb.y), wv[5], acc);
      __half2 t2 = hmin2(__hmul2(acc, mk2), hi2);
      __half2 e = h2exp2(t2);
      __half2 th = __hmul2(__hsub2(one2, e), h2rcp(__hadd2(one2, e)));
      int byte = tt * 256 + ((4 * l) ^ ((tt & 7) << 4));
      *(unsigned int*)(aw_base + byte) = h2u(th);
    }
    // no barrier: wave-private rows, in-order DS pipe
    // ---- phase 2: 4 K-steps of MFMA on this half ----
    #pragma unroll
    for (int ks = 0; ks < 4; ++ks) {
      int kof = ks * 64 + q * 16;           // byte offset of k-chunk in half
      int kob = half * 256 + kof;           // byte offset within full K row
      half8 a  = *(const half8*)(aw_base + col * 256 + (kof ^ arow_xor));
      half8 b0 = *(const half8*)(Bb + r0 * 512 + (kob ^ ((r0 & 7) << 4)));
      half8 b1 = *(const half8*)(Bb + r1 * 512 + (kob ^ ((r1 & 7) << 4)));
      half8 b2 = *(const half8*)(Bb + r2 * 512 + (kob ^ ((r2 & 7) << 4)));
      acc0 = __builtin_amdgcn_mfma_f32_16x16x32_f16(a, b0, acc0, 0, 0, 0);
      acc1 = __builtin_amdgcn_mfma_f32_16x16x32_f16(a, b1, acc1, 0, 0, 0);
      acc2 = __builtin_amdgcn_mfma_f32_16x16x32_f16(a, b2, acc2, 0, 0, 0);
    }
  }

  // ---- epilogue: transform + transpose into 8B records in wave scratch ----
  float b2_0 = bt2[col], b2_1 = bt2[16 + col], b2_2 = bt2[32 + col];
  int c3 = col % 3;
  int ob0 = (3 - c3) % 3;              // ob with p==0
  int ob1 = (ob0 + 1) % 3;             // p==1
  int ob2 = (ob0 + 2) % 3;             // p==2
  int h0 = (16 * ob0 + col) / 3;
  int h1 = (16 * ob1 + col) / 3;
  int h2 = (16 * ob2 + col) / 3;
  #pragma unroll
  for (int i = 0; i < 4; ++i) {
    int tt = q * 4 + i;
    int t = t0 + w * 16 + tt;
    if (t >= NTT) continue;
    float2 pe = *(const float2*)&xe[w * 16 + tt][0];  // plv, Evp
    float vv0 = acc0[i] + b2_0, vv1 = acc1[i] + b2_1, vv2 = acc2[i] + b2_2;
    float s0 = (ob0 == 0) ? vv0 : (ob0 == 1) ? vv1 : vv2;
    float s1 = (ob1 == 0) ? vv0 : (ob1 == 1) ? vv1 : vv2;
    float s2 = (ob2 == 0) ? vv0 : (ob2 == 1) ? vv1 : vv2;
    char* rowp = aw_base + tt * 128;
    *(__half*)(rowp + h0 * 8 + 0) = __float2half(pe.x * fsig(s0));   // pli
    *(__half*)(rowp + h1 * 8 + 2) = __float2half(fmaxf(s1, 0.f));    // fm
    *(__half*)(rowp + h2 * 8 + 4) = __float2half(pe.y * __expf(s2)); // ev
  }
  // read back 8B records, insert ps, store to global (wave-private rows)
  #pragma unroll
  for (int k2 = 0; k2 < 4; ++k2) {
    int idx = k2 * 64 + l;             // 0..255 over wave's 16t x 16h
    int tt = idx >> 4, h = idx & 15;
    int t = t0 + w * 16 + tt;
    if (t < NTT) {
      u16x4 r4 = *(const u16x4*)(aw_base + tt * 128 + h * 8);
      __half psh = __float2half(xe[w * 16 + tt][2]);
      r4[3] = *(unsigned short*)&psh;
      *(u16x4*)&recP[((size_t)t * 8000 + s * 16 + h) * 4] = r4;
    }
  }
}

// --- sequential bucket scan: asm loads + counted vmcnt; q output via LDS ---
// 6 chunks x 8 records in flight (48 loads); s_waitcnt vmcnt(40) per phase
// retires exactly the chunk about to be consumed (loop has NO other vmcnt
// traffic: q goes to LDS via compiler ds_write -> lgkmcnt domain; the
// R10 NaN was store-data VGPR reuse while asm global_store was in flight).
struct Rec8 { u32x2 r[8]; };

__device__ __forceinline__ void issue8(Rec8& c, int tb, int tid,
                                       const char* recP)
{
  #pragma unroll
  for (int u = 0; u < 8; ++u) {
    int t = tb + u; t = t < NTT ? t : NTT - 1;   // clamp: values discarded
    unsigned long long addr =
        (unsigned long long)(recP + ((size_t)t * 8000 + tid) * 8);
    asm volatile("global_load_dwordx2 %0, %1, off"
                 : "=v"(c.r[u]) : "v"(addr));
  }
}

__device__ __forceinline__ void comp8(
    const Rec8& c, int tb, u32x4* Qlds4, int lane,
    float& Sf, float& Ss, float& Sd,
    float kp, float ksf, float kg, float gr, float gL, float qb, float omgr)
{
  float qv[8];
  #pragma unroll
  for (int u = 0; u < 8; ++u) {
    float pli = h2f((unsigned short)(c.r[u].x & 0xffff));
    float fm  = h2f((unsigned short)(c.r[u].x >> 16));
    float ev  = h2f((unsigned short)(c.r[u].y & 0xffff));
    float ps  = h2f((unsigned short)(c.r[u].y >> 16));
    float ce  = pli - ev;                 // off the dependency chain
    float S1 = Sf + ps;
    float qf = fminf(S1, fm);
    Sf = S1 - qf;
    float S2 = fmaxf((Ss + ce) + qf, 0.f);
    float qp = fmaxf(S2 - gL, 0.f) * kp;
    float qs = fminf(S2, gL) * ksf;
    Ss = S2 - qp - qs;
    float S3 = fmaf(qs, gr, Sd);
    float qd = fmaf(S3, kg, qb);
    Sd = fmaxf(S3 - qd, 0.f);
    qv[u] = fmaf(qs, omgr, qp) + qd;
  }
  if (tb < NTT) {
    u32x4 q4;
    q4.x = h2u(__floats2half2_rn(qv[0], qv[1]));
    q4.y = h2u(__floats2half2_rn(qv[2], qv[3]));
    q4.z = h2u(__floats2half2_rn(qv[4], qv[5]));
    q4.w = h2u(__floats2half2_rn(qv[6], qv[7]));
    Qlds4[(tb >> 3) * 64 + lane] = q4;   // lanes consecutive 16B: conflict-free
  }
}

#define SCAN_PHASE(CK, OFF) \
  asm volatile("s_waitcnt vmcnt(40)" ::: "memory"); \
  __builtin_amdgcn_sched_barrier(0); \
  comp8(CK, tb + OFF, Qlds4, lane, Sf, Ss, Sd, kp, ksf, kg, gr, gL, qb, omgr); \
  issue8(CK, tb + 48 + OFF, tid, rb); \
  __builtin_amdgcn_sched_barrier(0);

__global__ __launch_bounds__(64, 1) void scan_kernel(
    const float* __restrict__ params,
    const unsigned short* __restrict__ recP,
    __half* __restrict__ Qg2)
{
  __shared__ u32x4 Qlds4[125 * 64];          // 128,000 B: q[chunk][lane]
  int lane = threadIdx.x;
  int tid = blockIdx.x * 64 + lane;          // 125 blocks x 64 = 8000
  const float* P = params + tid * 6;
  float kp = P[0], ksf = P[1], kg = P[2], gr = P[3], gL = P[4], qb = P[5];
  float omgr = 1.f - gr;
  // pin the params waitcnt OUTSIDE the loop (dummy uses force the compiler
  // to consider the values materialized here)
  asm volatile("" : "+v"(kp), "+v"(ksf), "+v"(kg), "+v"(gr), "+v"(gL));
  asm volatile("" : "+v"(qb), "+v"(omgr));
  asm volatile("s_waitcnt vmcnt(0)" ::: "memory");
  __builtin_amdgcn_sched_barrier(0);

  float Sf = 0.f, Ss = 0.f, Sd = 0.f;
  const char* rb = (const char*)recP;

  Rec8 C0, C1, C2, C3, C4, C5;
  issue8(C0,  0, tid, rb);
  issue8(C1,  8, tid, rb);
  issue8(C2, 16, tid, rb);
  issue8(C3, 24, tid, rb);
  issue8(C4, 32, tid, rb);
  issue8(C5, 40, tid, rb);
  __builtin_amdgcn_sched_barrier(0);
  // 21 iters x 48 steps = 1008 >= 1000 (tail clamped/guarded)
  for (int i = 0; i < 21; ++i) {
    int tb = i * 48;
    SCAN_PHASE(C0,  0)
    SCAN_PHASE(C1,  8)
    SCAN_PHASE(C2, 16)
    SCAN_PHASE(C3, 24)
    SCAN_PHASE(C4, 32)
    SCAN_PHASE(C5, 40)
  }
  // drain trailing asm loads before reusing anything / ending the wave
  asm volatile("s_waitcnt vmcnt(0)" ::: "memory");
  __builtin_amdgcn_sched_barrier(0);
  // copy LDS -> global chain-major [8000][1024]; lane owns its chain:
  // ds_read lanes consecutive within a row (conflict-free); L2 merges the
  // 16B/2048B-stride stores into full lines.
  size_t gbase = (size_t)tid * 1024;
  for (int k = 0; k < 125; ++k) {
    u32x4 v = Qlds4[k * 64 + lane];
    *(u32x4*)(Qg2 + gbase + k * 8) = v;
  }
}

// ------------- unit-hydrograph routing + bucket mixture -------------
// Q is chain-major [8000][1024]. LDS Qs[h][tt] pitch 144 (not %32-critical):
// inner read Qs[hh][row] has lanes on consecutive tt -> consecutive banks.
__global__ __launch_bounds__(128) void route_kernel(
    const __half* __restrict__ Qg2, const float* __restrict__ rg,
    float* __restrict__ out)
{
  int s = blockIdx.x;
  int t0 = WARM + blockIdx.y * 128;
  int tid = threadIdx.x;
  __shared__ float Qs[16][144];
  __shared__ float rgs[16][16];   // [j][h]
  {
    int h = tid >> 3, part = tid & 7;
    const __half* src = Qg2 + (size_t)(s * 16 + h) * 1024 + (t0 - 15);
    for (int k = part; k < 143; k += 8)
      Qs[h][k] = __half2float(src[k]);
  }
  for (int i = tid; i < 256; i += 128) {
    int h = i >> 4, j = i & 15;
    rgs[j][h] = rg[s * 256 + i];
  }
  __syncthreads();
  int t = t0 + tid;
  if (t < NTT) {
    float acc = 0.f;
    #pragma unroll
    for (int j = 0; j < 16; ++j) {
      int row = tid + 15 - j;
      #pragma unroll
      for (int h = 0; h < 16; ++h)
        acc = fmaf(Qs[h][row], rgs[j][h], acc);
    }
    out[(t - WARM) * NSB + s] = acc;
  }
}

extern "C" void kernel_launch(void* const* d_in, const int* in_sizes, int n_in,
                              void* d_out, int out_size, void* d_ws, size_t ws_size,
                              hipStream_t stream)
{
  const float* x   = (const float*)d_in[0];
  const float* xc  = (const float*)d_in[1];
  const float* Wr1 = (const float*)d_in[2];
  const float* br1 = (const float*)d_in[3];
  const float* Wr2 = (const float*)d_in[4];
  const float* br2 = (const float*)d_in[5];
  const float* Ww1 = (const float*)d_in[6];
  const float* bw1 = (const float*)d_in[7];
  const float* Ww2 = (const float*)d_in[8];
  const float* bw2 = (const float*)d_in[9];
  const float* Wt1 = (const float*)d_in[10];
  const float* bt1 = (const float*)d_in[11];
  const float* Wt2 = (const float*)d_in[12];
  const float* bt2 = (const float*)d_in[13];

  char* w = (char*)d_ws;
  unsigned short* recP = (unsigned short*)(w);     // 64,000,000 B (8B/record)
  __half* Qg2   = (__half*)(w + 64000000);         // 16,384,000 B [8000][1024]
  float*  params= (float*)(w + 80384000);          //    192,000 B
  float*  rgw   = (float*)(w + 80576000);          //    512,000 B
  _Float16* BT  = (_Float16*)(w + 81088000);       //     24,576 B
  _Float16* W1h = (_Float16*)(w + 81112576);       //      3,072 B
  _Float16* c_gh= (_Float16*)(w + 81115648);       //    256,000 B

  prep_bt_kernel<<<48, 256, 0, stream>>>(Wt2, Wt1, BT, W1h);
  static_kernel<<<500, 256, 0, stream>>>(xc, Wr1, br1, Wr2, br2,
                                         Ww1, bw1, Ww2, bw2, Wt1, bt1,
                                         c_gh, params, rgw);
  tv_kernel<<<dim3(500, 16), 256, 0, stream>>>(x, W1h, bt2, c_gh, BT, recP);
  scan_kernel<<<125, 64, 0, stream>>>(params, recP, Qg2);
  route_kernel<<<dim3(500, 3), 128, 0, stream>>>(Qg2, rgw, (float*)d_out);
}

// Round 12
// 171.767 us; speedup vs baseline: 1.2139x; 1.0683x over previous
//
#include <hip/hip_runtime.h>
#include <hip/hip_fp16.h>

typedef __attribute__((ext_vector_type(8))) _Float16 half8;
typedef __attribute__((ext_vector_type(2))) _Float16 h2v;
typedef __attribute__((ext_vector_type(4))) float f32x4;
typedef __attribute__((ext_vector_type(4))) unsigned short u16x4;
typedef __attribute__((ext_vector_type(2))) unsigned int u32x2;
typedef __attribute__((ext_vector_type(4))) unsigned int u32x4;

#define NTT 1000
#define NSB 500
#define WARM 639

__device__ __forceinline__ float fsig(float x) {
  return __builtin_amdgcn_rcpf(1.f + __expf(-x));
}
// tanh(x) = 2/(1+e^(-2x)) - 1 ; branchless, inf-safe (f32)
__device__ __forceinline__ float ftanh(float x) {
  float e = __expf(-2.f * x);
  return fmaf(2.f, __builtin_amdgcn_rcpf(1.f + e), -1.f);
}
__device__ __forceinline__ float h2f(unsigned short u) {
  __half_raw hr; hr.x = u;
  return __half2float((__half)hr);
}
__device__ __forceinline__ __half2 u2h(unsigned int u) {
  __half2 h; *(unsigned int*)&h = u; return h;
}
__device__ __forceinline__ unsigned int h2u(__half2 h) {
  return *(unsigned int*)&h;
}
// packed f16 min (no __hmin2 in HIP headers) -> v_pk_min_f16
__device__ __forceinline__ __half2 hmin2(__half2 a, __half2 b) {
  h2v av = *(h2v*)&a, bv = *(h2v*)&b;
  h2v r = __builtin_elementwise_min(av, bv);
  return *(__half2*)&r;
}

// ---- prep: Wt2 -> f16 transposed XOR-swizzled [48][256]; Wt1 rows0-5 -> f16 ----
__global__ void prep_bt_kernel(const float* __restrict__ Wt2,
                               const float* __restrict__ Wt1,
                               _Float16* __restrict__ BT,
                               _Float16* __restrict__ W1h) {
  int i = blockIdx.x * 256 + threadIdx.x;
  if (i < 48 * 256) {
    int o = i >> 8, k = i & 255;
    int byte = o * 512 + ((k * 2) ^ ((o & 7) << 4));
    *(_Float16*)((char*)BT + byte) = (_Float16)Wt2[k * 48 + o];
  }
  if (i < 1536) W1h[i] = (_Float16)Wt1[i];   // rows 0..5 of Wt1 = first 1536
}

// ------------- static per-basin params (one block per basin) -------------
__global__ __launch_bounds__(256) void static_kernel(
    const float* __restrict__ xc,
    const float* __restrict__ Wr1, const float* __restrict__ br1,
    const float* __restrict__ Wr2, const float* __restrict__ br2,
    const float* __restrict__ Ww1, const float* __restrict__ bw1,
    const float* __restrict__ Ww2, const float* __restrict__ bw2,
    const float* __restrict__ Wt1, const float* __restrict__ bt1,
    _Float16* __restrict__ c_gh, float* __restrict__ params,
    float* __restrict__ rg)
{
  int s = blockIdx.x, tid = threadIdx.x;
  __shared__ float xcs[32];
  __shared__ float hw[256], hr[256];
  __shared__ float wout[112], rout[256];
  if (tid < 32) xcs[tid] = xc[s * 32 + tid];
  __syncthreads();
  {
    float aw = bw1[tid], ar = br1[tid], ac = bt1[tid];
    #pragma unroll 8
    for (int g = 0; g < 32; ++g) {
      float v = xcs[g];
      aw = fmaf(v, Ww1[g * 256 + tid], aw);
      ar = fmaf(v, Wr1[g * 256 + tid], ar);
      ac = fmaf(v, Wt1[(6 + g) * 256 + tid], ac);
    }
    hw[tid] = ftanh(aw);
    hr[tid] = ftanh(ar);
    c_gh[s * 256 + tid] = (_Float16)ac;   // time-invariant layer-1 preact (f16)
  }
  __syncthreads();
  {
    float acc = br2[tid];
    #pragma unroll 8
    for (int k = 0; k < 256; ++k) acc = fmaf(hr[k], Wr2[k * 256 + tid], acc);
    rout[tid] = acc;
  }
  if (tid < 112) {
    float acc = bw2[tid];
    #pragma unroll 8
    for (int k = 0; k < 256; ++k) acc = fmaf(hw[k], Ww2[k * 112 + tid], acc);
    wout[tid] = acc;
  }
  __syncthreads();
  if (tid < 16) {
    int h = tid;
    float* P = params + (s * 16 + h) * 6;
    P[0] = fsig(wout[h * 7 + 0]);           // kp
    P[1] = fsig(wout[h * 7 + 1]);           // ksf
    P[2] = fsig(wout[h * 7 + 2]);           // kg
    P[3] = fsig(wout[h * 7 + 3]);           // gr
    P[4] = __expf(wout[h * 7 + 4]);         // gL
    P[5] = fmaxf(wout[h * 7 + 5], 0.f);     // qb
    float m = -1e30f;
    for (int k = 0; k < 16; ++k) m = fmaxf(m, wout[k * 7 + 6]);
    float den = 0.f;
    for (int k = 0; k < 16; ++k) den += __expf(wout[k * 7 + 6] - m);
    float ga = __expf(wout[h * 7 + 6] - m) * __builtin_amdgcn_rcpf(den);
    float rm = -1e30f;
    for (int j = 0; j < 16; ++j) rm = fmaxf(rm, rout[h * 16 + j]);
    float rden = 0.f;
    for (int j = 0; j < 16; ++j) rden += __expf(rout[h * 16 + j] - rm);
    float sc = ga * __builtin_amdgcn_rcpf(rden);
    for (int j = 0; j < 16; ++j)
      rg[(s * 16 + h) * 16 + j] = __expf(rout[h * 16 + j] - rm) * sc;
  }
}

// ------------- time-varying MLP -------------
// Bbuf staged one K-half at a time (12 KB): LDS 31.8 KB -> 5 blocks/CU.
__global__ __launch_bounds__(256, 5) void tv_kernel(
    const float* __restrict__ x, const _Float16* __restrict__ W1h,
    const float* __restrict__ bt2, const _Float16* __restrict__ c_gh,
    const _Float16* __restrict__ BTg,
    unsigned short* __restrict__ recP)
{
  int s = blockIdx.x;
  int t0 = blockIdx.y * 64;
  int tid = threadIdx.x;
  int w = tid >> 6, l = tid & 63;

  __shared__ _Float16 Abuf[4][16][128];   // 16 KB: per-wave transpose buf
  __shared__ _Float16 Bbuf[48 * 128];     // 12 KB: Wt2^T, one half, swizzled
  __shared__ __half2  xl2[64][8];         // 2 KB: broadcast x pairs (6 used)
  __shared__ float    xe[64][4];          // 1 KB: {plv, Evp, psn, 0}

  // ---- stage half 0 of Bbuf + x ----
  for (int i = tid; i < 768; i += 256) {
    int o = i >> 4, j = i & 15;
    *(half8*)((char*)Bbuf + o * 256 + j * 16) =
        *(const half8*)((const char*)BTg + o * 512 + j * 16);
  }
  if (tid < 64) {
    int t = t0 + tid;
    float2 a = {0.f, 0.f}, b = a, c = a;
    if (t < NTT) {
      const float* xp = &x[((size_t)t * NSB + s) * 6];
      a = *(const float2*)(xp + 0);   // Prcp, Evp
      b = *(const float2*)(xp + 2);   // T1, T2
      c = *(const float2*)(xp + 4);
    }
    float vp = fsig(0.5f * (b.x + b.y));
    xe[tid][0] = a.x * vp;            // pl
    xe[tid][1] = a.y;                 // Evp
    xe[tid][2] = a.x * (1.f - vp);    // ps
    xe[tid][3] = 0.f;
    xl2[tid][0] = __floats2half2_rn(a.x, a.x);
    xl2[tid][1] = __floats2half2_rn(a.y, a.y);
    xl2[tid][2] = __floats2half2_rn(b.x, b.x);
    xl2[tid][3] = __floats2half2_rn(b.y, b.y);
    xl2[tid][4] = __floats2half2_rn(c.x, c.x);
    xl2[tid][5] = __floats2half2_rn(c.y, c.y);
    xl2[tid][6] = __floats2half2_rn(0.f, 0.f);
    xl2[tid][7] = __floats2half2_rn(0.f, 0.f);
  }
  __syncthreads();

  // constants
  const __half2 one2 = __floats2half2_rn(1.f, 1.f);
  const __half2 mk2  = __floats2half2_rn(-2.88539008f, -2.88539008f); // -2*log2(e)
  const __half2 hi2  = __floats2half2_rn(15.5f, 15.5f);

  // per-lane layer-1 weights for both halves (cols 2l,2l+1 and +128), f16 direct
  __half2 wlo[6], whi[6];
  #pragma unroll
  for (int c = 0; c < 6; ++c) {
    wlo[c] = *(const __half2*)&W1h[c * 256 + 2 * l];
    whi[c] = *(const __half2*)&W1h[c * 256 + 128 + 2 * l];
  }
  __half2 cglo = *(const __half2*)&c_gh[s * 256 + 2 * l];
  __half2 cghi = *(const __half2*)&c_gh[s * 256 + 128 + 2 * l];

  char* aw_base = (char*)&Abuf[w][0][0];
  int col = l & 15, q = l >> 4;
  int arow_xor = (col & 7) << 4;
  const char* Bb = (const char*)Bbuf;
  int r0 = 0 + col, r1 = 16 + col, r2 = 32 + col;
  f32x4 acc0 = {0.f, 0.f, 0.f, 0.f}, acc1 = acc0, acc2 = acc0;

  #pragma unroll
  for (int half = 0; half < 2; ++half) {
    if (half == 1) {
      __syncthreads();   // all waves done with Bbuf half0
      for (int i = tid; i < 768; i += 256) {
        int o = i >> 4, j = i & 15;
        *(half8*)((char*)Bbuf + o * 256 + j * 16) =
            *(const half8*)((const char*)BTg + o * 512 + 256 + j * 16);
      }
      __syncthreads();
    }
    const __half2* wv = half ? whi : wlo;
    __half2 cg2 = half ? cghi : cglo;
    // ---- phase 1: this wave's 16 rows, 128 cols ----
    #pragma unroll
    for (int tt = 0; tt < 16; ++tt) {
      int tr = w * 16 + tt;
      uint4 xa = *(const uint4*)&xl2[tr][0];
      uint2 xb = *(const uint2*)&xl2[tr][4];
      __half2 acc = cg2;
      acc = __hfma2(u2h(xa.x), wv[0], acc);
      acc = __hfma2(u2h(xa.y), wv[1], acc);
      acc = __hfma2(u2h(xa.z), wv[2], acc);
      acc = __hfma2(u2h(xa.w), wv[3], acc);
      acc = __hfma2(u2h(xb.x), wv[4], acc);
      acc = __hfma2(u2h(xb.y), wv[5], acc);
      __half2 t2 = hmin2(__hmul2(acc, mk2), hi2);
      __half2 e = h2exp2(t2);
      __half2 th = __hmul2(__hsub2(one2, e), h2rcp(__hadd2(one2, e)));
      int byte = tt * 256 + ((4 * l) ^ ((tt & 7) << 4));
      *(unsigned int*)(aw_base + byte) = h2u(th);
    }
    // no barrier: wave-private rows, in-order DS pipe
    // ---- phase 2: 4 K-steps of MFMA on this half ----
    #pragma unroll
    for (int ks = 0; ks < 4; ++ks) {
      int kof = ks * 64 + q * 16;           // byte offset of k-chunk in half
      half8 a  = *(const half8*)(aw_base + col * 256 + (kof ^ arow_xor));
      half8 b0 = *(const half8*)(Bb + r0 * 256 + (kof ^ ((r0 & 7) << 4)));
      half8 b1 = *(const half8*)(Bb + r1 * 256 + (kof ^ ((r1 & 7) << 4)));
      half8 b2 = *(const half8*)(Bb + r2 * 256 + (kof ^ ((r2 & 7) << 4)));
      acc0 = __builtin_amdgcn_mfma_f32_16x16x32_f16(a, b0, acc0, 0, 0, 0);
      acc1 = __builtin_amdgcn_mfma_f32_16x16x32_f16(a, b1, acc1, 0, 0, 0);
      acc2 = __builtin_amdgcn_mfma_f32_16x16x32_f16(a, b2, acc2, 0, 0, 0);
    }
  }

  // ---- epilogue: transform + transpose into 8B records in wave scratch ----
  float b2_0 = bt2[col], b2_1 = bt2[16 + col], b2_2 = bt2[32 + col];
  int c3 = col % 3;
  int ob0 = (3 - c3) % 3;              // ob with p==0
  int ob1 = (ob0 + 1) % 3;             // p==1
  int ob2 = (ob0 + 2) % 3;             // p==2
  int h0 = (16 * ob0 + col) / 3;
  int h1 = (16 * ob1 + col) / 3;
  int h2 = (16 * ob2 + col) / 3;
  #pragma unroll
  for (int i = 0; i < 4; ++i) {
    int tt = q * 4 + i;
    int t = t0 + w * 16 + tt;
    if (t >= NTT) continue;
    float2 pe = *(const float2*)&xe[w * 16 + tt][0];  // plv, Evp
    float vv0 = acc0[i] + b2_0, vv1 = acc1[i] + b2_1, vv2 = acc2[i] + b2_2;
    float s0 = (ob0 == 0) ? vv0 : (ob0 == 1) ? vv1 : vv2;
    float s1 = (ob1 == 0) ? vv0 : (ob1 == 1) ? vv1 : vv2;
    float s2 = (ob2 == 0) ? vv0 : (ob2 == 1) ? vv1 : vv2;
    char* rowp = aw_base + tt * 128;
    *(__half*)(rowp + h0 * 8 + 0) = __float2half(pe.x * fsig(s0));   // pli
    *(__half*)(rowp + h1 * 8 + 2) = __float2half(fmaxf(s1, 0.f));    // fm
    *(__half*)(rowp + h2 * 8 + 4) = __float2half(pe.y * __expf(s2)); // ev
  }
  // read back 8B records, insert ps, store to global (wave-private rows)
  #pragma unroll
  for (int k2 = 0; k2 < 4; ++k2) {
    int idx = k2 * 64 + l;             // 0..255 over wave's 16t x 16h
    int tt = idx >> 4, h = idx & 15;
    int t = t0 + w * 16 + tt;
    if (t < NTT) {
      u16x4 r4 = *(const u16x4*)(aw_base + tt * 128 + h * 8);
      __half psh = __float2half(xe[w * 16 + tt][2]);
      r4[3] = *(unsigned short*)&psh;
      *(u16x4*)&recP[((size_t)t * 8000 + s * 16 + h) * 4] = r4;
    }
  }
}

// --- sequential bucket scan: asm loads + counted vmcnt; q output via LDS ---
struct Rec8 { u32x2 r[8]; };

__device__ __forceinline__ void issue8(Rec8& c, int tb, int tid,
                                       const char* recP)
{
  #pragma unroll
  for (int u = 0; u < 8; ++u) {
    int t = tb + u; t = t < NTT ? t : NTT - 1;   // clamp: values discarded
    unsigned long long addr =
        (unsigned long long)(recP + ((size_t)t * 8000 + tid) * 8);
    asm volatile("global_load_dwordx2 %0, %1, off"
                 : "=v"(c.r[u]) : "v"(addr));
  }
}

__device__ __forceinline__ void comp8(
    const Rec8& c, int tb, u32x4* Qlds4, int lane,
    float& Sf, float& Ss, float& Sd,
    float kp, float ksf, float kg, float gr, float gL, float qb, float omgr)
{
  float qv[8];
  #pragma unroll
  for (int u = 0; u < 8; ++u) {
    float pli = h2f((unsigned short)(c.r[u].x & 0xffff));
    float fm  = h2f((unsigned short)(c.r[u].x >> 16));
    float ev  = h2f((unsigned short)(c.r[u].y & 0xffff));
    float ps  = h2f((unsigned short)(c.r[u].y >> 16));
    float ce  = pli - ev;                 // off the dependency chain
    float S1 = Sf + ps;
    float qf = fminf(S1, fm);
    Sf = S1 - qf;
    float S2 = fmaxf((Ss + ce) + qf, 0.f);
    float qp = fmaxf(S2 - gL, 0.f) * kp;
    float qs = fminf(S2, gL) * ksf;
    Ss = S2 - qp - qs;
    float S3 = fmaf(qs, gr, Sd);
    float qd = fmaf(S3, kg, qb);
    Sd = fmaxf(S3 - qd, 0.f);
    qv[u] = fmaf(qs, omgr, qp) + qd;
  }
  if (tb < NTT) {
    u32x4 q4;
    q4.x = h2u(__floats2half2_rn(qv[0], qv[1]));
    q4.y = h2u(__floats2half2_rn(qv[2], qv[3]));
    q4.z = h2u(__floats2half2_rn(qv[4], qv[5]));
    q4.w = h2u(__floats2half2_rn(qv[6], qv[7]));
    Qlds4[(tb >> 3) * 64 + lane] = q4;   // lanes consecutive 16B: conflict-free
  }
}

#define SCAN_PHASE(CK, OFF) \
  asm volatile("s_waitcnt vmcnt(40)" ::: "memory"); \
  __builtin_amdgcn_sched_barrier(0); \
  comp8(CK, tb + OFF, Qlds4, lane, Sf, Ss, Sd, kp, ksf, kg, gr, gL, qb, omgr); \
  issue8(CK, tb + 48 + OFF, tid, rb); \
  __builtin_amdgcn_sched_barrier(0);

__global__ __launch_bounds__(64, 1) void scan_kernel(
    const float* __restrict__ params,
    const unsigned short* __restrict__ recP,
    __half* __restrict__ Qg2)
{
  __shared__ u32x4 Qlds4[125 * 64];          // 128,000 B: q[chunk][lane]
  int lane = threadIdx.x;
  int tid = blockIdx.x * 64 + lane;          // 125 blocks x 64 = 8000
  const float* P = params + tid * 6;
  float kp = P[0], ksf = P[1], kg = P[2], gr = P[3], gL = P[4], qb = P[5];
  float omgr = 1.f - gr;
  // pin the params waitcnt OUTSIDE the loop (dummy uses force the compiler
  // to consider the values materialized here)
  asm volatile("" : "+v"(kp), "+v"(ksf), "+v"(kg), "+v"(gr), "+v"(gL));
  asm volatile("" : "+v"(qb), "+v"(omgr));
  asm volatile("s_waitcnt vmcnt(0)" ::: "memory");
  __builtin_amdgcn_sched_barrier(0);

  float Sf = 0.f, Ss = 0.f, Sd = 0.f;
  const char* rb = (const char*)recP;

  Rec8 C0, C1, C2, C3, C4, C5;
  issue8(C0,  0, tid, rb);
  issue8(C1,  8, tid, rb);
  issue8(C2, 16, tid, rb);
  issue8(C3, 24, tid, rb);
  issue8(C4, 32, tid, rb);
  issue8(C5, 40, tid, rb);
  __builtin_amdgcn_sched_barrier(0);
  // 21 iters x 48 steps = 1008 >= 1000 (tail clamped/guarded)
  for (int i = 0; i < 21; ++i) {
    int tb = i * 48;
    SCAN_PHASE(C0,  0)
    SCAN_PHASE(C1,  8)
    SCAN_PHASE(C2, 16)
    SCAN_PHASE(C3, 24)
    SCAN_PHASE(C4, 32)
    SCAN_PHASE(C5, 40)
  }
  // drain trailing asm loads before reusing anything / ending the wave
  asm volatile("s_waitcnt vmcnt(0)" ::: "memory");
  __builtin_amdgcn_sched_barrier(0);
  // copy LDS -> global chain-major [8000][1024]
  size_t gbase = (size_t)tid * 1024;
  for (int k = 0; k < 125; ++k) {
    u32x4 v = Qlds4[k * 64 + lane];
    *(u32x4*)(Qg2 + gbase + k * 8) = v;
  }
}

// ------------- unit-hydrograph routing + bucket mixture -------------
// Q is chain-major [8000][1024]. 16B-aligned half8 loads (t0-15 is even and
// byte offset %16==0 for all y-blocks); 18 chunks x 8 halves = 144 fits row.
__global__ __launch_bounds__(128) void route_kernel(
    const __half* __restrict__ Qg2, const float* __restrict__ rg,
    float* __restrict__ out)
{
  int s = blockIdx.x;
  int t0 = WARM + blockIdx.y * 128;
  int tid = threadIdx.x;
  __shared__ float Qs[16][144];
  __shared__ float rgs[16][16];   // [j][h]
  {
    int h = tid & 15, c = tid >> 4;          // c in 0..7
    const __half* src = Qg2 + (size_t)(s * 16 + h) * 1024 + (t0 - 15);
    #pragma unroll
    for (int cc = 0; cc < 3; ++cc) {
      int ch = c + cc * 8;
      if (ch < 18) {
        half8 v8 = *(const half8*)(src + ch * 8);
        #pragma unroll
        for (int j = 0; j < 8; ++j) {
          int idx = ch * 8 + j;
          if (idx < 143) Qs[h][idx] = (float)v8[j];
        }
      }
    }
  }
  for (int i = tid; i < 256; i += 128) {
    int h = i >> 4, j = i & 15;
    rgs[j][h] = rg[s * 256 + i];
  }
  __syncthreads();
  int t = t0 + tid;
  if (t < NTT) {
    float acc = 0.f;
    #pragma unroll
    for (int j = 0; j < 16; ++j) {
      int row = tid + 15 - j;
      #pragma unroll
      for (int h = 0; h < 16; ++h)
        acc = fmaf(Qs[h][row], rgs[j][h], acc);
    }
    out[(t - WARM) * NSB + s] = acc;
  }
}

extern "C" void kernel_launch(void* const* d_in, const int* in_sizes, int n_in,
                              void* d_out, int out_size, void* d_ws, size_t ws_size,
                              hipStream_t stream)
{
  const float* x   = (const float*)d_in[0];
  const float* xc  = (const float*)d_in[1];
  const float* Wr1 = (const float*)d_in[2];
  const float* br1 = (const float*)d_in[3];
  const float* Wr2 = (const float*)d_in[4];
  const float* br2 = (const float*)d_in[5];
  const float* Ww1 = (const float*)d_in[6];
  const float* bw1 = (const float*)d_in[7];
  const float* Ww2 = (const float*)d_in[8];
  const float* bw2 = (const float*)d_in[9];
  const float* Wt1 = (const float*)d_in[10];
  const float* bt1 = (const float*)d_in[11];
  const float* Wt2 = (const float*)d_in[12];
  const float* bt2 = (const float*)d_in[13];

  char* w = (char*)d_ws;
  unsigned short* recP = (unsigned short*)(w);     // 64,000,000 B (8B/record)
  __half* Qg2   = (__half*)(w + 64000000);         // 16,384,000 B [8000][1024]
  float*  params= (float*)(w + 80384000);          //    192,000 B
  float*  rgw   = (float*)(w + 80576000);          //    512,000 B
  _Float16* BT  = (_Float16*)(w + 81088000);       //     24,576 B
  _Float16* W1h = (_Float16*)(w + 81112576);       //      3,072 B
  _Float16* c_gh= (_Float16*)(w + 81115648);       //    256,000 B

  prep_bt_kernel<<<48, 256, 0, stream>>>(Wt2, Wt1, BT, W1h);
  static_kernel<<<500, 256, 0, stream>>>(xc, Wr1, br1, Wr2, br2,
                                         Ww1, bw1, Ww2, bw2, Wt1, bt1,
                                         c_gh, params, rgw);
  tv_kernel<<<dim3(500, 16), 256, 0, stream>>>(x, W1h, bt2, c_gh, BT, recP);
  scan_kernel<<<125, 64, 0, stream>>>(params, recP, Qg2);
  route_kernel<<<dim3(500, 3), 128, 0, stream>>>(Qg2, rgw, (float*)d_out);
}

// Round 13
// 158.636 us; speedup vs baseline: 1.3144x; 1.0828x over previous
//
#include <hip/hip_runtime.h>
#include <hip/hip_fp16.h>

typedef __attribute__((ext_vector_type(8))) _Float16 half8;
typedef __attribute__((ext_vector_type(2))) _Float16 h2v;
typedef __attribute__((ext_vector_type(4))) float f32x4;
typedef __attribute__((ext_vector_type(4))) unsigned short u16x4;
typedef __attribute__((ext_vector_type(2))) unsigned int u32x2;
typedef __attribute__((ext_vector_type(4))) unsigned int u32x4;

#define NTT 1000
#define NSB 500
#define WARM 639
#define MKF (-2.8853900817779268f)   // -2*log2(e)

__device__ __forceinline__ float fsig(float x) {
  return __builtin_amdgcn_rcpf(1.f + __expf(-x));
}
__device__ __forceinline__ float ftanh(float x) {
  float e = __expf(-2.f * x);
  return fmaf(2.f, __builtin_amdgcn_rcpf(1.f + e), -1.f);
}
__device__ __forceinline__ float h2f(unsigned short u) {
  __half_raw hr; hr.x = u;
  return __half2float((__half)hr);
}
__device__ __forceinline__ __half2 u2h(unsigned int u) {
  __half2 h; *(unsigned int*)&h = u; return h;
}
__device__ __forceinline__ unsigned int h2u(__half2 h) {
  return *(unsigned int*)&h;
}
// packed f16 min (no __hmin2 in HIP headers) -> v_pk_min_f16
__device__ __forceinline__ __half2 hmin2(__half2 a, __half2 b) {
  h2v av = *(h2v*)&a, bv = *(h2v*)&b;
  h2v r = __builtin_elementwise_min(av, bv);
  return *(__half2*)&r;
}

// ------------- static per-basin params (+prep in blocks 0-47) -------------
__global__ __launch_bounds__(256) void static_kernel(
    const float* __restrict__ xc,
    const float* __restrict__ Wr1, const float* __restrict__ br1,
    const float* __restrict__ Wr2, const float* __restrict__ br2,
    const float* __restrict__ Ww1, const float* __restrict__ bw1,
    const float* __restrict__ Ww2, const float* __restrict__ bw2,
    const float* __restrict__ Wt1, const float* __restrict__ bt1,
    const float* __restrict__ Wt2, const float* __restrict__ bt2,
    _Float16* __restrict__ c_gh, float* __restrict__ params,
    float* __restrict__ rg,
    _Float16* __restrict__ BT, _Float16* __restrict__ W1h,
    float* __restrict__ bS)
{
  int s = blockIdx.x, tid = threadIdx.x;
  __shared__ float xcs[32];
  __shared__ float hw[256], hr[256];
  __shared__ float wout[112], rout[256];
  if (tid < 32) xcs[tid] = xc[s * 32 + tid];
  __syncthreads();
  {
    float aw = bw1[tid], ar = br1[tid], ac = bt1[tid];
    #pragma unroll 8
    for (int g = 0; g < 32; ++g) {
      float v = xcs[g];
      aw = fmaf(v, Ww1[g * 256 + tid], aw);
      ar = fmaf(v, Wr1[g * 256 + tid], ar);
      ac = fmaf(v, Wt1[(6 + g) * 256 + tid], ac);
    }
    hw[tid] = ftanh(aw);
    hr[tid] = ftanh(ar);
    // pre-scaled by -2*log2(e): phase-1 preact lands directly in exp2 domain
    c_gh[s * 256 + tid] = (_Float16)(ac * MKF);
  }
  __syncthreads();
  {
    float acc = br2[tid];
    #pragma unroll 8
    for (int k = 0; k < 256; ++k) acc = fmaf(hr[k], Wr2[k * 256 + tid], acc);
    rout[tid] = acc;
  }
  if (tid < 112) {
    float acc = bw2[tid];
    #pragma unroll 8
    for (int k = 0; k < 256; ++k) acc = fmaf(hw[k], Ww2[k * 112 + tid], acc);
    wout[tid] = acc;
  }
  __syncthreads();
  if (tid < 16) {
    int h = tid;
    float* P = params + (s * 16 + h) * 6;
    P[0] = fsig(wout[h * 7 + 0]);           // kp
    P[1] = fsig(wout[h * 7 + 1]);           // ksf
    P[2] = fsig(wout[h * 7 + 2]);           // kg
    P[3] = fsig(wout[h * 7 + 3]);           // gr
    P[4] = __expf(wout[h * 7 + 4]);         // gL
    P[5] = fmaxf(wout[h * 7 + 5], 0.f);     // qb
    float m = -1e30f;
    for (int k = 0; k < 16; ++k) m = fmaxf(m, wout[k * 7 + 6]);
    float den = 0.f;
    for (int k = 0; k < 16; ++k) den += __expf(wout[k * 7 + 6] - m);
    float ga = __expf(wout[h * 7 + 6] - m) * __builtin_amdgcn_rcpf(den);
    float rm = -1e30f;
    for (int j = 0; j < 16; ++j) rm = fmaxf(rm, rout[h * 16 + j]);
    float rden = 0.f;
    for (int j = 0; j < 16; ++j) rden += __expf(rout[h * 16 + j] - rm);
    float sc = ga * __builtin_amdgcn_rcpf(rden);
    for (int j = 0; j < 16; ++j)
      rg[(s * 16 + h) * 16 + j] = __expf(rout[h * 16 + j] - rm) * sc;
  }
  // ---- prep section (blocks 0..47): BT, W1h, bS ----
  if (s < 48) {
    int o = s, k = tid;
    float w2v = Wt2[k * 48 + o];
    int byte = o * 512 + ((k * 2) ^ ((o & 7) << 4));
    *(_Float16*)((char*)BT + byte) = (_Float16)w2v;
    if (s < 6) W1h[s * 256 + tid] = (_Float16)(Wt1[s * 256 + tid] * MKF);
    __syncthreads();                 // prior hw reads complete
    hw[tid] = w2v;
    __syncthreads();
    for (int st = 128; st > 0; st >>= 1) {
      if (tid < st) hw[tid] += hw[tid + st];
      __syncthreads();
    }
    if (tid == 0) bS[o] = bt2[o] - hw[0];   // v = 2*acc + bS
  }
}

// ------------- time-varying MLP -------------
// phase1: sigma(2p) via pre-scaled weights: min, 2*exp2, add, 2*rcp per pair
// layer2: f16 MFMA on sigma values; epilogue v = 2*acc + bS
__global__ __launch_bounds__(256, 5) void tv_kernel(
    const float* __restrict__ x, const _Float16* __restrict__ W1h,
    const float* __restrict__ bS, const _Float16* __restrict__ c_gh,
    const _Float16* __restrict__ BTg,
    unsigned short* __restrict__ recP)
{
  int s = blockIdx.x;
  int t0 = blockIdx.y * 64;
  int tid = threadIdx.x;
  int w = tid >> 6, l = tid & 63;

  __shared__ _Float16 Abuf[4][16][128];   // 16 KB: per-wave transpose buf
  __shared__ _Float16 Bbuf[48 * 128];     // 12 KB: Wt2^T, one half, swizzled
  __shared__ __half2  xl2[64][8];         // 2 KB: broadcast x pairs (6 used)
  __shared__ float    xe[64][4];          // 1 KB: {plv, Evp, psn, 0}

  // ---- stage half 0 of Bbuf + x ----
  for (int i = tid; i < 768; i += 256) {
    int o = i >> 4, j = i & 15;
    *(half8*)((char*)Bbuf + o * 256 + j * 16) =
        *(const half8*)((const char*)BTg + o * 512 + j * 16);
  }
  if (tid < 64) {
    int t = t0 + tid;
    float2 a = {0.f, 0.f}, b = a, c = a;
    if (t < NTT) {
      const float* xp = &x[((size_t)t * NSB + s) * 6];
      a = *(const float2*)(xp + 0);   // Prcp, Evp
      b = *(const float2*)(xp + 2);   // T1, T2
      c = *(const float2*)(xp + 4);
    }
    float vp = fsig(0.5f * (b.x + b.y));
    xe[tid][0] = a.x * vp;            // pl
    xe[tid][1] = a.y;                 // Evp
    xe[tid][2] = a.x * (1.f - vp);    // ps
    xe[tid][3] = 0.f;
    xl2[tid][0] = __floats2half2_rn(a.x, a.x);
    xl2[tid][1] = __floats2half2_rn(a.y, a.y);
    xl2[tid][2] = __floats2half2_rn(b.x, b.x);
    xl2[tid][3] = __floats2half2_rn(b.y, b.y);
    xl2[tid][4] = __floats2half2_rn(c.x, c.x);
    xl2[tid][5] = __floats2half2_rn(c.y, c.y);
    xl2[tid][6] = __floats2half2_rn(0.f, 0.f);
    xl2[tid][7] = __floats2half2_rn(0.f, 0.f);
  }
  __syncthreads();

  const __half2 one2 = __floats2half2_rn(1.f, 1.f);
  const __half2 hi2  = __floats2half2_rn(15.5f, 15.5f);

  // per-lane layer-1 weights (pre-scaled), cols 2l,2l+1 and +128
  __half2 wlo[6], whi[6];
  #pragma unroll
  for (int c = 0; c < 6; ++c) {
    wlo[c] = *(const __half2*)&W1h[c * 256 + 2 * l];
    whi[c] = *(const __half2*)&W1h[c * 256 + 128 + 2 * l];
  }
  __half2 cglo = *(const __half2*)&c_gh[s * 256 + 2 * l];
  __half2 cghi = *(const __half2*)&c_gh[s * 256 + 128 + 2 * l];

  char* aw_base = (char*)&Abuf[w][0][0];
  int col = l & 15, q = l >> 4;
  int arow_xor = (col & 7) << 4;
  const char* Bb = (const char*)Bbuf;
  int r0 = 0 + col, r1 = 16 + col, r2 = 32 + col;
  f32x4 acc0 = {0.f, 0.f, 0.f, 0.f}, acc1 = acc0, acc2 = acc0;

  #pragma unroll
  for (int half = 0; half < 2; ++half) {
    if (half == 1) {
      __syncthreads();   // all waves done with Bbuf half0
      for (int i = tid; i < 768; i += 256) {
        int o = i >> 4, j = i & 15;
        *(half8*)((char*)Bbuf + o * 256 + j * 16) =
            *(const half8*)((const char*)BTg + o * 512 + 256 + j * 16);
      }
      __syncthreads();
    }
    const __half2* wv = half ? whi : wlo;
    __half2 cg2 = half ? cghi : cglo;
    // ---- phase 1: sigma for this wave's 16 rows, 128 cols ----
    #pragma unroll
    for (int tt = 0; tt < 16; ++tt) {
      int tr = w * 16 + tt;
      uint4 xa = *(const uint4*)&xl2[tr][0];
      uint2 xb = *(const uint2*)&xl2[tr][4];
      __half2 acc = cg2;
      acc = __hfma2(u2h(xa.x), wv[0], acc);
      acc = __hfma2(u2h(xa.y), wv[1], acc);
      acc = __hfma2(u2h(xa.z), wv[2], acc);
      acc = __hfma2(u2h(xa.w), wv[3], acc);
      acc = __hfma2(u2h(xb.x), wv[4], acc);
      acc = __hfma2(u2h(xb.y), wv[5], acc);
      // acc = -2*log2(e)*p ; e = exp2(acc) = exp(-2p); sigma = 1/(1+e)
      __half2 e = h2exp2(hmin2(acc, hi2));
      __half2 sg = h2rcp(__hadd2(one2, e));
      int byte = tt * 256 + ((4 * l) ^ ((tt & 7) << 4));
      *(unsigned int*)(aw_base + byte) = h2u(sg);
    }
    // no barrier: wave-private rows, in-order DS pipe
    // ---- phase 2: 4 K-steps of MFMA on this half ----
    #pragma unroll
    for (int ks = 0; ks < 4; ++ks) {
      int kof = ks * 64 + q * 16;           // byte offset of k-chunk in half
      half8 a  = *(const half8*)(aw_base + col * 256 + (kof ^ arow_xor));
      half8 b0 = *(const half8*)(Bb + r0 * 256 + (kof ^ ((r0 & 7) << 4)));
      half8 b1 = *(const half8*)(Bb + r1 * 256 + (kof ^ ((r1 & 7) << 4)));
      half8 b2 = *(const half8*)(Bb + r2 * 256 + (kof ^ ((r2 & 7) << 4)));
      acc0 = __builtin_amdgcn_mfma_f32_16x16x32_f16(a, b0, acc0, 0, 0, 0);
      acc1 = __builtin_amdgcn_mfma_f32_16x16x32_f16(a, b1, acc1, 0, 0, 0);
      acc2 = __builtin_amdgcn_mfma_f32_16x16x32_f16(a, b2, acc2, 0, 0, 0);
    }
  }

  // ---- epilogue: v = 2*acc + bS, transform, transpose into 8B records ----
  float bs0 = bS[col], bs1 = bS[16 + col], bs2 = bS[32 + col];
  int c3 = col % 3;
  int ob0 = (3 - c3) % 3;              // ob with p==0
  int ob1 = (ob0 + 1) % 3;             // p==1
  int ob2 = (ob0 + 2) % 3;             // p==2
  int h0 = (16 * ob0 + col) / 3;
  int h1 = (16 * ob1 + col) / 3;
  int h2 = (16 * ob2 + col) / 3;
  #pragma unroll
  for (int i = 0; i < 4; ++i) {
    int tt = q * 4 + i;
    int t = t0 + w * 16 + tt;
    if (t >= NTT) continue;
    float2 pe = *(const float2*)&xe[w * 16 + tt][0];  // plv, Evp
    float vv0 = fmaf(2.f, acc0[i], bs0);
    float vv1 = fmaf(2.f, acc1[i], bs1);
    float vv2 = fmaf(2.f, acc2[i], bs2);
    float s0 = (ob0 == 0) ? vv0 : (ob0 == 1) ? vv1 : vv2;
    float s1 = (ob1 == 0) ? vv0 : (ob1 == 1) ? vv1 : vv2;
    float s2 = (ob2 == 0) ? vv0 : (ob2 == 1) ? vv1 : vv2;
    char* rowp = aw_base + tt * 128;
    *(__half*)(rowp + h0 * 8 + 0) = __float2half(pe.x * fsig(s0));   // pli
    *(__half*)(rowp + h1 * 8 + 2) = __float2half(fmaxf(s1, 0.f));    // fm
    *(__half*)(rowp + h2 * 8 + 4) = __float2half(pe.y * __expf(s2)); // ev
  }
  // read back 8B records, insert ps, store to global (wave-private rows)
  #pragma unroll
  for (int k2 = 0; k2 < 4; ++k2) {
    int idx = k2 * 64 + l;             // 0..255 over wave's 16t x 16h
    int tt = idx >> 4, h = idx & 15;
    int t = t0 + w * 16 + tt;
    if (t < NTT) {
      u16x4 r4 = *(const u16x4*)(aw_base + tt * 128 + h * 8);
      __half psh = __float2half(xe[w * 16 + tt][2]);
      r4[3] = *(unsigned short*)&psh;
      *(u16x4*)&recP[((size_t)t * 8000 + s * 16 + h) * 4] = r4;
    }
  }
}

// --- sequential bucket scan: asm loads + counted vmcnt; q output via LDS ---
// Addressing: uniform SGPR base per t-row (SALU, co-issues) + constant
// voffset = tid*8. No clamp: t in [1000,1056) reads harmless bytes past
// recP (Qg2 region, valid f16 / 0xAA -> tiny values, results discarded).
struct Rec8 { u32x2 r[8]; };

__device__ __forceinline__ void issue8(Rec8& c, int tB, unsigned voff,
                                       const char* recP)
{
  #pragma unroll
  for (int u = 0; u < 8; ++u) {
    const char* base = recP + (size_t)(tB + u) * 64000;   // uniform -> SALU
    asm volatile("global_load_dwordx2 %0, %1, %2 offset:0"
                 : "=v"(c.r[u]) : "v"(voff), "s"(base));
  }
}

__device__ __forceinline__ void comp8(
    const Rec8& c, int tb, u32x4* Qlds4, int lane,
    float& Sf, float& Ss, float& Sd,
    float kp, float ksf, float kg, float gr, float gL, float qb, float omgr)
{
  float qv[8];
  #pragma unroll
  for (int u = 0; u < 8; ++u) {
    float pli = h2f((unsigned short)(c.r[u].x & 0xffff));
    float fm  = h2f((unsigned short)(c.r[u].x >> 16));
    float ev  = h2f((unsigned short)(c.r[u].y & 0xffff));
    float ps  = h2f((unsigned short)(c.r[u].y >> 16));
    float ce  = pli - ev;                 // off the dependency chain
    float S1 = Sf + ps;
    float qf = fminf(S1, fm);
    Sf = S1 - qf;
    float S2 = fmaxf((Ss + ce) + qf, 0.f);
    float qp = fmaxf(S2 - gL, 0.f) * kp;
    float qs = fminf(S2, gL) * ksf;
    Ss = S2 - qp - qs;
    float S3 = fmaf(qs, gr, Sd);
    float qd = fmaf(S3, kg, qb);
    Sd = fmaxf(S3 - qd, 0.f);
    qv[u] = fmaf(qs, omgr, qp) + qd;
  }
  if (tb < NTT) {
    u32x4 q4;
    q4.x = h2u(__floats2half2_rn(qv[0], qv[1]));
    q4.y = h2u(__floats2half2_rn(qv[2], qv[3]));
    q4.z = h2u(__floats2half2_rn(qv[4], qv[5]));
    q4.w = h2u(__floats2half2_rn(qv[6], qv[7]));
    Qlds4[(tb >> 3) * 64 + lane] = q4;   // lanes consecutive 16B: conflict-free
  }
}

#define SCAN_PHASE(CK, OFF) \
  asm volatile("s_waitcnt vmcnt(40)" ::: "memory"); \
  __builtin_amdgcn_sched_barrier(0); \
  comp8(CK, tb + OFF, Qlds4, lane, Sf, Ss, Sd, kp, ksf, kg, gr, gL, qb, omgr); \
  issue8(CK, tb + 48 + OFF, voff, rb); \
  __builtin_amdgcn_sched_barrier(0);

__global__ __launch_bounds__(64, 1) void scan_kernel(
    const float* __restrict__ params,
    const unsigned short* __restrict__ recP,
    __half* __restrict__ Qg2)
{
  __shared__ u32x4 Qlds4[125 * 64];          // 128,000 B: q[chunk][lane]
  int lane = threadIdx.x;
  int tid = blockIdx.x * 64 + lane;          // 125 blocks x 64 = 8000
  unsigned voff = (unsigned)tid * 8;
  const float* P = params + tid * 6;
  float kp = P[0], ksf = P[1], kg = P[2], gr = P[3], gL = P[4], qb = P[5];
  float omgr = 1.f - gr;
  asm volatile("" : "+v"(kp), "+v"(ksf), "+v"(kg), "+v"(gr), "+v"(gL));
  asm volatile("" : "+v"(qb), "+v"(omgr));
  asm volatile("s_waitcnt vmcnt(0)" ::: "memory");
  __builtin_amdgcn_sched_barrier(0);

  float Sf = 0.f, Ss = 0.f, Sd = 0.f;
  const char* rb = (const char*)recP;

  Rec8 C0, C1, C2, C3, C4, C5;
  issue8(C0,  0, voff, rb);
  issue8(C1,  8, voff, rb);
  issue8(C2, 16, voff, rb);
  issue8(C3, 24, voff, rb);
  issue8(C4, 32, voff, rb);
  issue8(C5, 40, voff, rb);
  __builtin_amdgcn_sched_barrier(0);
  // 21 iters x 48 steps = 1008 >= 1000 (tail guarded; prefetch reads junk)
  for (int i = 0; i < 21; ++i) {
    int tb = i * 48;
    SCAN_PHASE(C0,  0)
    SCAN_PHASE(C1,  8)
    SCAN_PHASE(C2, 16)
    SCAN_PHASE(C3, 24)
    SCAN_PHASE(C4, 32)
    SCAN_PHASE(C5, 40)
  }
  asm volatile("s_waitcnt vmcnt(0)" ::: "memory");
  __builtin_amdgcn_sched_barrier(0);
  // copy LDS -> global chain-major [8000][1024]
  size_t gbase = (size_t)tid * 1024;
  for (int k = 0; k < 125; ++k) {
    u32x4 v = Qlds4[k * 64 + lane];
    *(u32x4*)(Qg2 + gbase + k * 8) = v;
  }
}

// ------------- unit-hydrograph routing + bucket mixture -------------
// Q is chain-major [8000][1024]. Qs pitch 145 (coprime with 32 banks).
__global__ __launch_bounds__(128) void route_kernel(
    const __half* __restrict__ Qg2, const float* __restrict__ rg,
    float* __restrict__ out)
{
  int s = blockIdx.x;
  int t0 = WARM + blockIdx.y * 128;
  int tid = threadIdx.x;
  __shared__ float Qs[16][145];
  __shared__ float rgs[16][16];   // [j][h]
  {
    int h = tid & 15, c = tid >> 4;          // c in 0..7
    const __half* src = Qg2 + (size_t)(s * 16 + h) * 1024 + (t0 - 15);
    #pragma unroll
    for (int cc = 0; cc < 3; ++cc) {
      int ch = c + cc * 8;
      if (ch < 18) {
        half8 v8 = *(const half8*)(src + ch * 8);
        #pragma unroll
        for (int j = 0; j < 8; ++j) {
          int idx = ch * 8 + j;
          if (idx < 143) Qs[h][idx] = (float)v8[j];
        }
      }
    }
  }
  for (int i = tid; i < 256; i += 128) {
    int h = i >> 4, j = i & 15;
    rgs[j][h] = rg[s * 256 + i];
  }
  __syncthreads();
  int t = t0 + tid;
  if (t < NTT) {
    float acc = 0.f;
    #pragma unroll
    for (int j = 0; j < 16; ++j) {
      int row = tid + 15 - j;
      #pragma unroll
      for (int h = 0; h < 16; ++h)
        acc = fmaf(Qs[h][row], rgs[j][h], acc);
    }
    out[(t - WARM) * NSB + s] = acc;
  }
}

extern "C" void kernel_launch(void* const* d_in, const int* in_sizes, int n_in,
                              void* d_out, int out_size, void* d_ws, size_t ws_size,
                              hipStream_t stream)
{
  const float* x   = (const float*)d_in[0];
  const float* xc  = (const float*)d_in[1];
  const float* Wr1 = (const float*)d_in[2];
  const float* br1 = (const float*)d_in[3];
  const float* Wr2 = (const float*)d_in[4];
  const float* br2 = (const float*)d_in[5];
  const float* Ww1 = (const float*)d_in[6];
  const float* bw1 = (const float*)d_in[7];
  const float* Ww2 = (const float*)d_in[8];
  const float* bw2 = (const float*)d_in[9];
  const float* Wt1 = (const float*)d_in[10];
  const float* bt1 = (const float*)d_in[11];
  const float* Wt2 = (const float*)d_in[12];
  const float* bt2 = (const float*)d_in[13];

  char* w = (char*)d_ws;
  unsigned short* recP = (unsigned short*)(w);     // 64,000,000 B (8B/record)
  __half* Qg2   = (__half*)(w + 64000000);         // 16,384,000 B [8000][1024]
  float*  params= (float*)(w + 80384000);          //    192,000 B
  float*  rgw   = (float*)(w + 80576000);          //    512,000 B
  _Float16* BT  = (_Float16*)(w + 81088000);       //     24,576 B
  _Float16* W1h = (_Float16*)(w + 81112576);       //      3,072 B
  _Float16* c_gh= (_Float16*)(w + 81115648);       //    256,000 B
  float*  bS    = (float*)(w + 81371648);          //        192 B

  static_kernel<<<500, 256, 0, stream>>>(xc, Wr1, br1, Wr2, br2,
                                         Ww1, bw1, Ww2, bw2, Wt1, bt1,
                                         Wt2, bt2,
                                         c_gh, params, rgw, BT, W1h, bS);
  tv_kernel<<<dim3(500, 16), 256, 0, stream>>>(x, W1h, bS, c_gh, BT, recP);
  scan_kernel<<<125, 64, 0, stream>>>(params, recP, Qg2);
  route_kernel<<<dim3(500, 3), 128, 0, stream>>>(Qg2, rgw, (float*)d_out);
}